// Round 1
// baseline (396.077 us; speedup 1.0000x reference)
//
#include <hip/hip_runtime.h>
#include <hip/hip_cooperative_groups.h>
#include <math.h>

namespace cg = cooperative_groups;

typedef __bf16 bf16_t;
typedef bf16_t bf16x4 __attribute__((ext_vector_type(4)));
typedef bf16_t bf16x8 __attribute__((ext_vector_type(8)));
typedef float  f32x4  __attribute__((ext_vector_type(4)));

__device__ __forceinline__ float softplus_f(float x) {
    return (x > 20.f) ? x : log1pf(expf(x));
}

__device__ __forceinline__ float fast_rcp(float x) {
#if __has_builtin(__builtin_amdgcn_rcpf)
    return __builtin_amdgcn_rcpf(x);
#else
    return 1.0f / x;
#endif
}

// ============================================================================
// Shared attention body (verified attn_v7 structure), used by both paths.
// ============================================================================
#define OFF_VM   0
#define OFF_VV   36864
#define OFF_FS   73728
#define OFF_SC   82176
#define OFF_PHI  98816
#define OFF_PLO  107264
#define OFF_P2H  115712
#define OFF_P2L  124160
#define ATTN_SMEM 132608

__device__ void attn_body(unsigned char* smem, const int t, const int qt, const int h,
                          const float* __restrict__ Qm, const float* __restrict__ Qv,
                          const bf16_t* __restrict__ Gbf, const float* __restrict__ cvec,
                          const float* __restrict__ Vm, const float* __restrict__ Vv,
                          bf16_t* __restrict__ Omu, bf16_t* __restrict__ Ovar) {
    bf16_t* Vsm = (bf16_t*)(smem + OFF_VM);   // [256][72] bf16
    bf16_t* Vsv = (bf16_t*)(smem + OFF_VV);
    float*  Fs  = (float*)(smem + OFF_FS);    // [16][132] f32
    float*  Sc  = (float*)(smem + OFF_SC);    // [16][260] f32
    bf16_t* Phi = (bf16_t*)(smem + OFF_PHI);  // [16][264] bf16
    bf16_t* Plo = (bf16_t*)(smem + OFF_PLO);
    bf16_t* P2h = (bf16_t*)(smem + OFF_P2H);
    bf16_t* P2l = (bf16_t*)(smem + OFF_P2L);

    const int w = t >> 6, lane = t & 63;
    const int fr = lane & 15, fq = lane >> 4;
    const int n0 = w * 32;

    const bf16_t* gB = Gbf + ((size_t)(h * 256 + n0 + fr)) * 128 + fq * 8;

    bf16x8 bcur[4];
#pragma unroll
    for (int ks = 0; ks < 4; ++ks) bcur[ks] = *(const bf16x8*)(gB + ks * 32);

    if (t < 256) {
        const int r = t >> 4, c = t & 15;
        f32x4 qm = *(const f32x4*)(Qm + (size_t)(qt * 16 + r) * 1024 + h * 64 + c * 4);
        f32x4 qv = *(const f32x4*)(Qv + (size_t)(qt * 16 + r) * 1024 + h * 64 + c * 4);
        *(f32x4*)&Fs[r * 132 + c * 4]      = qm * qm + qv;
        *(f32x4*)&Fs[r * 132 + 64 + c * 4] = qm;
    }
    __syncthreads();

    bf16x8 ahi[4], alo[4];
#pragma unroll
    for (int ks = 0; ks < 4; ++ks) {
        f32x4 f0 = *(const f32x4*)&Fs[fr * 132 + ks * 32 + fq * 8];
        f32x4 f1 = *(const f32x4*)&Fs[fr * 132 + ks * 32 + fq * 8 + 4];
#pragma unroll
        for (int e = 0; e < 4; ++e) {
            bf16_t hb = (bf16_t)f0[e];
            ahi[ks][e] = hb; alo[ks][e] = (bf16_t)(f0[e] - (float)hb);
            bf16_t hb2 = (bf16_t)f1[e];
            ahi[ks][e + 4] = hb2; alo[ks][e + 4] = (bf16_t)(f1[e] - (float)hb2);
        }
    }

    const int tm = t & 255;
    const int vk = tm >> 2, vpart = tm & 3;
    const float* Vsrc = (t >= 256) ? Vv : Vm;
    bf16_t*      Vdst = (t >= 256) ? Vsv : Vsm;

#pragma unroll
    for (int nt = 0; nt < 2; ++nt) {
        const int ra = vk + (2 * nt) * 64;
        const int rb = vk + (2 * nt + 1) * 64;
        const float* vsa = Vsrc + (size_t)ra * 1024 + h * 64 + vpart * 16;
        const float* vsb = Vsrc + (size_t)rb * 1024 + h * 64 + vpart * 16;
        f32x4 va0 = *(const f32x4*)(vsa),     va1 = *(const f32x4*)(vsa + 4);
        f32x4 va2 = *(const f32x4*)(vsa + 8), va3 = *(const f32x4*)(vsa + 12);
        f32x4 vb0 = *(const f32x4*)(vsb),     vb1 = *(const f32x4*)(vsb + 4);
        f32x4 vb2 = *(const f32x4*)(vsb + 8), vb3 = *(const f32x4*)(vsb + 12);

        bf16x8 bnxt[4];
        if (nt < 1) {
#pragma unroll
            for (int ks = 0; ks < 4; ++ks)
                bnxt[ks] = *(const bf16x8*)(gB + 2048 + ks * 32);
        }

        f32x4 acc = {0.f, 0.f, 0.f, 0.f};
#pragma unroll
        for (int ks = 0; ks < 4; ++ks) {
            acc = __builtin_amdgcn_mfma_f32_16x16x32_bf16(ahi[ks], bcur[ks], acc, 0, 0, 0);
            acc = __builtin_amdgcn_mfma_f32_16x16x32_bf16(alo[ks], bcur[ks], acc, 0, 0, 0);
        }

        {
            bf16_t* da = Vdst + ra * 72 + vpart * 16;
            bf16_t* db = Vdst + rb * 72 + vpart * 16;
            bf16x8 o0, o1;
            o0[0]=(bf16_t)va0[0]; o0[1]=(bf16_t)va0[1]; o0[2]=(bf16_t)va0[2]; o0[3]=(bf16_t)va0[3];
            o0[4]=(bf16_t)va1[0]; o0[5]=(bf16_t)va1[1]; o0[6]=(bf16_t)va1[2]; o0[7]=(bf16_t)va1[3];
            o1[0]=(bf16_t)va2[0]; o1[1]=(bf16_t)va2[1]; o1[2]=(bf16_t)va2[2]; o1[3]=(bf16_t)va2[3];
            o1[4]=(bf16_t)va3[0]; o1[5]=(bf16_t)va3[1]; o1[6]=(bf16_t)va3[2]; o1[7]=(bf16_t)va3[3];
            *(bf16x8*)(da)     = o0;
            *(bf16x8*)(da + 8) = o1;
            o0[0]=(bf16_t)vb0[0]; o0[1]=(bf16_t)vb0[1]; o0[2]=(bf16_t)vb0[2]; o0[3]=(bf16_t)vb0[3];
            o0[4]=(bf16_t)vb1[0]; o0[5]=(bf16_t)vb1[1]; o0[6]=(bf16_t)vb1[2]; o0[7]=(bf16_t)vb1[3];
            o1[0]=(bf16_t)vb2[0]; o1[1]=(bf16_t)vb2[1]; o1[2]=(bf16_t)vb2[2]; o1[3]=(bf16_t)vb2[3];
            o1[4]=(bf16_t)vb3[0]; o1[5]=(bf16_t)vb3[1]; o1[6]=(bf16_t)vb3[2]; o1[7]=(bf16_t)vb3[3];
            *(bf16x8*)(db)     = o0;
            *(bf16x8*)(db + 8) = o1;
        }

        const float cv = cvec[h * 256 + n0 + nt * 16 + fr];
        f32x4 lg = (acc + cv) * (-0.125f);
#pragma unroll
        for (int reg = 0; reg < 4; ++reg)
            Sc[(fq * 4 + reg) * 260 + n0 + nt * 16 + fr] = lg[reg];

#pragma unroll
        for (int ks = 0; ks < 4; ++ks) bcur[ks] = bnxt[ks];
    }
    __syncthreads();

    const int fw = w * 2;
    f32x4 sr[2];
#pragma unroll
    for (int r = 0; r < 2; ++r)
        sr[r] = *(const f32x4*)&Sc[(fw + r) * 260 + lane * 4];
#pragma unroll
    for (int r = 0; r < 2; ++r) {
        f32x4 s = sr[r];
        float mloc = fmaxf(fmaxf(s[0], s[1]), fmaxf(s[2], s[3]));
#pragma unroll
        for (int off = 32; off > 0; off >>= 1)
            mloc = fmaxf(mloc, __shfl_xor(mloc, off, 64));
        s[0] = __expf(s[0] - mloc); s[1] = __expf(s[1] - mloc);
        s[2] = __expf(s[2] - mloc); s[3] = __expf(s[3] - mloc);
        float sl = (s[0] + s[1]) + (s[2] + s[3]);
#pragma unroll
        for (int off = 32; off > 0; off >>= 1)
            sl += __shfl_xor(sl, off, 64);
        sr[r] = s * fast_rcp(sl);
    }

#pragma unroll
    for (int r = 0; r < 2; ++r) {
        bf16x4 phi, plo, p2hi, p2lo;
#pragma unroll
        for (int e = 0; e < 4; ++e) {
            const float p = sr[r][e];
            const bf16_t hb = (bf16_t)p;
            phi[e] = hb; plo[e] = (bf16_t)(p - (float)hb);
            const float p2 = p * p;
            const bf16_t h2 = (bf16_t)p2;
            p2hi[e] = h2; p2lo[e] = (bf16_t)(p2 - (float)h2);
        }
        const int row = fw + r;
        *(bf16x4*)&Phi[row * 264 + lane * 4] = phi;
        *(bf16x4*)&Plo[row * 264 + lane * 4] = plo;
        *(bf16x4*)&P2h[row * 264 + lane * 4] = p2hi;
        *(bf16x4*)&P2l[row * 264 + lane * 4] = p2lo;
    }
    __syncthreads();

    const int tile = w & 3;
    const int isvar = w >> 2;
    const bf16_t* Pa = isvar ? P2h : Phi;
    const bf16_t* Pb = isvar ? P2l : Plo;
    const bf16_t* Vs = isvar ? Vsv : Vsm;
    f32x4 accp = {0.f, 0.f, 0.f, 0.f};
#pragma unroll
    for (int k0 = 0; k0 < 256; k0 += 32) {
        const int ka = k0 + fq * 8;
        bf16x8 a1 = *(const bf16x8*)&Pa[fr * 264 + ka];
        bf16x8 a2 = *(const bf16x8*)&Pb[fr * 264 + ka];
        bf16x8 bfr;
#pragma unroll
        for (int j = 0; j < 8; ++j)
            bfr[j] = Vs[(ka + j) * 72 + tile * 16 + fr];
        accp = __builtin_amdgcn_mfma_f32_16x16x32_bf16(a1, bfr, accp, 0, 0, 0);
        accp = __builtin_amdgcn_mfma_f32_16x16x32_bf16(a2, bfr, accp, 0, 0, 0);
    }

    bf16_t* Out = isvar ? Ovar : Omu;
#pragma unroll
    for (int reg = 0; reg < 4; ++reg) {
        const int qg = qt * 16 + fq * 4 + reg;
        const size_t ob = (size_t)qg * 1024 + h * 64 + tile * 16 + fr;
        Out[ob] = (bf16_t)accp[reg];
    }
}

// ============================================================================
// Fused cooperative kernel: 256 blocks x 512 threads, 1 block/CU.
//   phase1: weight transpose+convert (2 tiles/iter, 4 iters)
//   phase2: projections; K-projection fused with feat (Gbf/cvec), Km/Kv never
//           materialized; A read directly as f32 (no activation prep pass)
//   phase3: attention (verified attn_v7 body)
//   phase4: output projections
// ============================================================================
#define FUSED_SMEM 147456   // 8 waves x (As 4608 + Bs 4608) bf16 = gemm stage; Cr = 8*4352 f32

struct FusedArgs {
    const float* mu; const float* var;
    const float* W[8];     // wq_mu, wq_var, wk_mu, wk_var, wv_mu, wv_var, wo_mu, wo_var
    const float* Bias[8];
    bf16_t* WtB;           // 8 x [1024 n][1024 k] bf16
    float*  Proj;          // 4 x 256 KB f32: Qm, Qv, Vm, Vv
    bf16_t* Obm; bf16_t* Obv;
    bf16_t* Gbf; float* cvec;
    float* out_mu; float* out_var;
};

// 64x64 tile GEMM, 8-wave split-K (K=128/wave, 2 slices of 64), register prefetch.
// Layouts identical to the verified 4-wave gemm_splitk. out[i] = raw sum (no bias),
// thread t owns rows (t>>4)+i*32, cols (t&15)*4 .. +3.
template<bool AF32>
__device__ __forceinline__ void gemm_core(const void* Aptr, const bf16_t* __restrict__ Wt,
                                          const int m_base, const int n_base,
                                          unsigned char* smem, const int t, f32x4 out[2]) {
    __syncthreads();   // smem handoff from any previous user
    bf16_t* stage = (bf16_t*)smem;
    float*  Cr    = (float*)smem;
    const int lane = t & 63, w = t >> 6;
    bf16_t* As = stage + w * 9216;
    bf16_t* Bs = As + 4608;
    const int r8 = lane >> 3, kb = lane & 7;
    const int fr = lane & 15, fq = lane >> 4, fk = fq * 8;

    const bf16_t* Bb = Wt + (size_t)n_base * 1024 + w * 128 + kb * 8;
    const float*  Af = (const float*)Aptr  + (size_t)m_base * 1024 + w * 128 + kb * 8;
    const bf16_t* Ab = (const bf16_t*)Aptr + (size_t)m_base * 1024 + w * 128 + kb * 8;

    f32x4 acc[4][4] = {};
    bf16x8 pb[8];
    f32x4 paf0[8], paf1[8];
    bf16x8 pa[8];
#pragma unroll
    for (int i = 0; i < 8; ++i) {
        pb[i] = *(const bf16x8*)(Bb + (size_t)(i * 8 + r8) * 1024);
        if constexpr (AF32) {
            paf0[i] = *(const f32x4*)(Af + (size_t)(i * 8 + r8) * 1024);
            paf1[i] = *(const f32x4*)(Af + (size_t)(i * 8 + r8) * 1024 + 4);
        } else {
            pa[i] = *(const bf16x8*)(Ab + (size_t)(i * 8 + r8) * 1024);
        }
    }

#pragma unroll
    for (int s = 0; s < 2; ++s) {
#pragma unroll
        for (int i = 0; i < 8; ++i) {
            bf16x8 av;
            if constexpr (AF32) {
#pragma unroll
                for (int e = 0; e < 4; ++e) {
                    av[e]     = (bf16_t)paf0[i][e];
                    av[e + 4] = (bf16_t)paf1[i][e];
                }
            } else {
                av = pa[i];
            }
            *(bf16x8*)&As[(i * 8 + r8) * 72 + kb * 8] = av;
            *(bf16x8*)&Bs[(i * 8 + r8) * 72 + kb * 8] = pb[i];
        }
        if (s == 0) {   // prefetch slice 1, in flight during MFMA below
#pragma unroll
            for (int i = 0; i < 8; ++i) {
                pb[i] = *(const bf16x8*)(Bb + (size_t)(i * 8 + r8) * 1024 + 64);
                if constexpr (AF32) {
                    paf0[i] = *(const f32x4*)(Af + (size_t)(i * 8 + r8) * 1024 + 64);
                    paf1[i] = *(const f32x4*)(Af + (size_t)(i * 8 + r8) * 1024 + 68);
                } else {
                    pa[i] = *(const bf16x8*)(Ab + (size_t)(i * 8 + r8) * 1024 + 64);
                }
            }
        }
#pragma unroll
        for (int kh = 0; kh < 2; ++kh) {
            bf16x8 aF[4], bF[4];
#pragma unroll
            for (int i = 0; i < 4; ++i)
                aF[i] = *(const bf16x8*)&As[(i * 16 + fr) * 72 + kh * 32 + fk];
#pragma unroll
            for (int j = 0; j < 4; ++j)
                bF[j] = *(const bf16x8*)&Bs[(j * 16 + fr) * 72 + kh * 32 + fk];
#pragma unroll
            for (int i = 0; i < 4; ++i)
#pragma unroll
                for (int j = 0; j < 4; ++j)
                    acc[i][j] = __builtin_amdgcn_mfma_f32_16x16x32_bf16(aF[i], bF[j], acc[i][j], 0, 0, 0);
        }
    }

    __syncthreads();
    {
        float* Crw = Cr + w * 4352;
        const int orow = fq * 4;
#pragma unroll
        for (int i = 0; i < 4; ++i)
#pragma unroll
            for (int j = 0; j < 4; ++j)
#pragma unroll
                for (int rr = 0; rr < 4; ++rr)
                    Crw[(i * 16 + orow + rr) * 68 + j * 16 + fr] = acc[i][j][rr];
    }
    __syncthreads();

    const int cc = (t & 15) * 4;
#pragma unroll
    for (int i = 0; i < 2; ++i) {
        const int row = (t >> 4) + i * 32;
        f32x4 v = {0.f, 0.f, 0.f, 0.f};
#pragma unroll
        for (int sl = 0; sl < 8; ++sl)
            v += *(const f32x4*)&Cr[sl * 4352 + row * 68 + cc];
        out[i] = v;
    }
}

__device__ __forceinline__ void run_simple(const FusedArgs& a, unsigned char* smem,
                                           const int t, const int st) {
    const int z4 = st >> 6, rem = st & 63;
    const int nb = (rem >> 2) * 64, mb = (rem & 3) * 64;
    const int wi = (z4 < 2) ? z4 : (z4 + 2);   // 0,1,4,5 -> wq_mu, wq_var, wv_mu, wv_var
    const void* A = (z4 & 1) ? (const void*)a.var : (const void*)a.mu;
    f32x4 o[2];
    gemm_core<true>(A, a.WtB + (size_t)wi * 1048576, mb, nb, smem, t, o);
    const int cc = (t & 15) * 4;
    const f32x4 bv = *(const f32x4*)&a.Bias[wi][nb + cc];
    float* dst = a.Proj + (size_t)z4 * 262144;
    const int sp = z4 & 1;
#pragma unroll
    for (int i = 0; i < 2; ++i) {
        const int row = (t >> 4) + i * 32;
        f32x4 v = o[i] + bv;
        if (sp) {
            v[0] = softplus_f(v[0]); v[1] = softplus_f(v[1]);
            v[2] = softplus_f(v[2]); v[3] = softplus_f(v[3]);
        }
        *(f32x4*)&dst[(size_t)(mb + row) * 1024 + nb + cc] = v;
    }
}

// Fused K-projection: Km and Kv tiles for head h = n-tile, then feat math -> Gbf, cvec.
__device__ __forceinline__ void run_fusedK(const FusedArgs& a, unsigned char* smem,
                                           const int t, const int ft) {
    const int nb = (ft >> 2) * 64, mb = (ft & 3) * 64;
    const int h = ft >> 2;
    f32x4 okm[2], okv[2];
    gemm_core<true>(a.mu,  a.WtB + (size_t)2 * 1048576, mb, nb, smem, t, okm);
    gemm_core<true>(a.var, a.WtB + (size_t)3 * 1048576, mb, nb, smem, t, okv);
    const int cc = (t & 15) * 4;
    const f32x4 bkm = *(const f32x4*)&a.Bias[2][nb + cc];
    const f32x4 bkv = *(const f32x4*)&a.Bias[3][nb + cc];
    float cp[2];
#pragma unroll
    for (int i = 0; i < 2; ++i) {
        const int row = (t >> 4) + i * 32;
        const int katt = mb + row;
        const f32x4 km  = okm[i] + bkm;
        const f32x4 kvr = okv[i] + bkv;
        bf16x4 o1, o2;
        float c = 0.f;
#pragma unroll
        for (int e = 0; e < 4; ++e) {
            const float kv = softplus_f(kvr[e]);
            const float r  = 0.5f * fast_rcp(kv);
            o1[e] = (bf16_t)r;
            o2[e] = (bf16_t)(-2.f * km[e] * r);
            c += km[e] * km[e] * r + 0.5f * __logf(kv);
        }
        bf16_t* grow = a.Gbf + ((size_t)(h * 256 + katt)) * 128;
        *(bf16x4*)&grow[cc]      = o1;
        *(bf16x4*)&grow[64 + cc] = o2;
        cp[i] = c;
    }
    __syncthreads();                 // all Cr reads done; reuse smem for cvec reduce
    float* red = (float*)smem;       // [64][16]
#pragma unroll
    for (int i = 0; i < 2; ++i)
        red[((t >> 4) + i * 32) * 16 + (t & 15)] = cp[i];
    __syncthreads();
    if (t < 64) {
        float s = 0.f;
#pragma unroll
        for (int g = 0; g < 16; ++g) s += red[t * 16 + g];
        a.cvec[h * 256 + mb + t] = s;
    }
}

__global__ __launch_bounds__(512) void fused_all(FusedArgs a) {
    __shared__ __align__(16) unsigned char smem[FUSED_SMEM];
    cg::grid_group grid = cg::this_grid();
    const int blk = blockIdx.x;
    const int t = threadIdx.x;

    // ---------------- phase 1: weight transpose+convert ----------------
    {
        bf16_t* Ts = (bf16_t*)smem + (t >> 8) * 4608;   // [64][72] per half-block
        const int lt = t & 255;
        const int r0 = lt >> 4, c4 = (lt & 15) * 4;
        for (int it = 0; it < 4; ++it) {
            const int tt = blk * 8 + it * 2 + (t >> 8);   // 0..2047
            const int wm = tt >> 8, rem = tt & 255, kt = rem >> 4, nt = rem & 15;
            const float* __restrict__ W = a.W[wm];
            bf16_t* __restrict__ Wt = a.WtB + (size_t)wm * 1048576;
#pragma unroll
            for (int rep = 0; rep < 4; ++rep) {
                const int r = r0 + rep * 16;
                const float4 v = *(const float4*)&W[(size_t)(kt * 64 + r) * 1024 + nt * 64 + c4];
                Ts[(c4 + 0) * 72 + r] = (bf16_t)v.x;
                Ts[(c4 + 1) * 72 + r] = (bf16_t)v.y;
                Ts[(c4 + 2) * 72 + r] = (bf16_t)v.z;
                Ts[(c4 + 3) * 72 + r] = (bf16_t)v.w;
            }
            __syncthreads();
#pragma unroll
            for (int rep = 0; rep < 2; ++rep) {
                const int chunk = lt + rep * 256;
                const int n = chunk >> 3, kc = (chunk & 7) * 8;
                bf16x8 v = *(const bf16x8*)&Ts[n * 72 + kc];
                *(bf16x8*)&Wt[(size_t)(nt * 64 + n) * 1024 + kt * 64 + kc] = v;
            }
            __syncthreads();
        }
    }
    __threadfence();
    grid.sync();

    // ---------------- phase 2: projections (Qm,Qv,Vm,Vv simple; K fused w/ feat) ----
    if (blk < 192) {
        run_simple(a, smem, t, blk);
        if (blk < 64) run_simple(a, smem, t, 192 + blk);
    } else {
        run_fusedK(a, smem, t, blk - 192);
    }
    __threadfence();
    grid.sync();

    // ---------------- phase 3: attention ----------------
    attn_body(smem, t, blk >> 4, blk & 15,
              a.Proj, a.Proj + 262144, a.Gbf, a.cvec,
              a.Proj + 2 * 262144, a.Proj + 3 * 262144, a.Obm, a.Obv);
    __threadfence();
    grid.sync();

    // ---------------- phase 4: output projections ----------------
    if (blk < 128) {
        const int z = blk >> 6, rem = blk & 63;
        const int nb = (rem >> 2) * 64, mb = (rem & 3) * 64;
        f32x4 o[2];
        gemm_core<false>(z ? (const void*)a.Obv : (const void*)a.Obm,
                         a.WtB + (size_t)(6 + z) * 1048576, mb, nb, smem, t, o);
        const int cc = (t & 15) * 4;
        const f32x4 bv = *(const f32x4*)&a.Bias[6 + z][nb + cc];
        float* dst = z ? a.out_var : a.out_mu;
#pragma unroll
        for (int i = 0; i < 2; ++i) {
            const int row = (t >> 4) + i * 32;
            f32x4 v = o[i] + bv;
            if (z) {
                v[0] = softplus_f(v[0]); v[1] = softplus_f(v[1]);
                v[2] = softplus_f(v[2]); v[3] = softplus_f(v[3]);
            }
            *(f32x4*)&dst[(size_t)(mb + row) * 1024 + nb + cc] = v;
        }
    }
}

// ============================================================================
// Legacy 5-kernel path (verified) — fallback if cooperative launch is rejected.
// ============================================================================
struct PrepArgs { const float* src[8]; const float* mu; const float* var; };

__global__ __launch_bounds__(256) void prep_kernel(PrepArgs pa, bf16_t* __restrict__ wtbase,
                                                   bf16_t* __restrict__ dmu, bf16_t* __restrict__ dvar) {
    const int t = threadIdx.x;
    if (blockIdx.z == 8) {
        const int gid = (blockIdx.y * 16 + blockIdx.x) * 256 + t;
        const float* s; bf16_t* d; int off;
        if (gid < 32768) { s = pa.mu;  d = dmu;  off = gid * 8; }
        else             { s = pa.var; d = dvar; off = (gid - 32768) * 8; }
        float4 v0 = *(const float4*)(s + off);
        float4 v1 = *(const float4*)(s + off + 4);
        bf16x8 o;
        o[0] = (bf16_t)v0.x; o[1] = (bf16_t)v0.y; o[2] = (bf16_t)v0.z; o[3] = (bf16_t)v0.w;
        o[4] = (bf16_t)v1.x; o[5] = (bf16_t)v1.y; o[6] = (bf16_t)v1.z; o[7] = (bf16_t)v1.w;
        *(bf16x8*)(d + off) = o;
        return;
    }
    const int kt = blockIdx.x, nt = blockIdx.y, wm = blockIdx.z;
    const float* __restrict__ W = pa.src[wm];
    bf16_t* __restrict__ Wt = wtbase + (size_t)wm * 1048576;
    __shared__ bf16_t Ts[64][72];
    const int r0 = t >> 4, c4 = (t & 15) * 4;
#pragma unroll
    for (int rep = 0; rep < 4; ++rep) {
        const int r = r0 + rep * 16;
        const float4 v = *(const float4*)&W[(size_t)(kt * 64 + r) * 1024 + nt * 64 + c4];
        Ts[c4 + 0][r] = (bf16_t)v.x;
        Ts[c4 + 1][r] = (bf16_t)v.y;
        Ts[c4 + 2][r] = (bf16_t)v.z;
        Ts[c4 + 3][r] = (bf16_t)v.w;
    }
    __syncthreads();
#pragma unroll
    for (int rep = 0; rep < 2; ++rep) {
        const int chunk = t + rep * 256;
        const int n = chunk >> 3, kc = (chunk & 7) * 8;
        bf16x8 v = *(const bf16x8*)&Ts[n][kc];
        *(bf16x8*)&Wt[(size_t)(nt * 64 + n) * 1024 + kt * 64 + kc] = v;
    }
}

struct GemmArgs {
    const bf16_t* A[6];
    const bf16_t* Wt[6];
    const float*  bias[6];
    float*        dst[6];
    int           splus[6];
};

__global__ __launch_bounds__(256, 2) void gemm_splitk(GemmArgs args) {
    const int z = blockIdx.z;
    const bf16_t* __restrict__ A    = args.A[z];
    const bf16_t* __restrict__ Wt   = args.Wt[z];
    const float*  __restrict__ bias = args.bias[z];
    float*        __restrict__ dst  = args.dst[z];
    const int sp = args.splus[z];

    const int n_base = blockIdx.x * 64;
    const int m_base = blockIdx.y * 64;

    __shared__ __align__(16) unsigned char smem_raw[73728];
    bf16_t* stage = (bf16_t*)smem_raw;
    float*  Cr    = (float*)smem_raw;

    const int t = threadIdx.x;
    const int lane = t & 63;
    const int w = t >> 6;
    bf16_t* As = stage + w * 9216;
    bf16_t* Bs = As + 4608;

    const int r8 = lane >> 3, kb = lane & 7;
    const int fr = lane & 15, fq = lane >> 4, fk = fq * 8;

    const bf16_t* Ab = A  + (size_t)m_base * 1024 + w * 256 + kb * 8;
    const bf16_t* Bb = Wt + (size_t)n_base * 1024 + w * 256 + kb * 8;

    f32x4 acc[4][4] = {};

    bf16x8 pa[8], pb[8];
#pragma unroll
    for (int i = 0; i < 8; ++i) {
        pa[i] = *(const bf16x8*)(Ab + (size_t)(i * 8 + r8) * 1024);
        pb[i] = *(const bf16x8*)(Bb + (size_t)(i * 8 + r8) * 1024);
    }

#pragma unroll
    for (int s = 0; s < 4; ++s) {
#pragma unroll
        for (int i = 0; i < 8; ++i) {
            *(bf16x8*)&As[(i * 8 + r8) * 72 + kb * 8] = pa[i];
            *(bf16x8*)&Bs[(i * 8 + r8) * 72 + kb * 8] = pb[i];
        }
        if (s < 3) {
            const int off = (s + 1) * 64;
#pragma unroll
            for (int i = 0; i < 8; ++i) {
                pa[i] = *(const bf16x8*)(Ab + (size_t)(i * 8 + r8) * 1024 + off);
                pb[i] = *(const bf16x8*)(Bb + (size_t)(i * 8 + r8) * 1024 + off);
            }
        }
#pragma unroll
        for (int kh = 0; kh < 2; ++kh) {
            bf16x8 aF[4], bF[4];
#pragma unroll
            for (int i = 0; i < 4; ++i)
                aF[i] = *(const bf16x8*)&As[(i * 16 + fr) * 72 + kh * 32 + fk];
#pragma unroll
            for (int j = 0; j < 4; ++j)
                bF[j] = *(const bf16x8*)&Bs[(j * 16 + fr) * 72 + kh * 32 + fk];
#pragma unroll
            for (int i = 0; i < 4; ++i)
#pragma unroll
                for (int j = 0; j < 4; ++j)
                    acc[i][j] = __builtin_amdgcn_mfma_f32_16x16x32_bf16(aF[i], bF[j], acc[i][j], 0, 0, 0);
        }
    }

    __syncthreads();
    {
        float* Crw = Cr + w * 4352;
        const int orow = fq * 4;
#pragma unroll
        for (int i = 0; i < 4; ++i)
#pragma unroll
            for (int j = 0; j < 4; ++j)
#pragma unroll
                for (int rr = 0; rr < 4; ++rr)
                    Crw[(i * 16 + orow + rr) * 68 + j * 16 + fr] = acc[i][j][rr];
    }
    __syncthreads();

    const int cc = (t & 15) * 4;
    f32x4 bv4 = *(const f32x4*)&bias[n_base + cc];
#pragma unroll
    for (int i = 0; i < 4; ++i) {
        const int row = (t >> 4) + i * 16;
        f32x4 s0 = *(const f32x4*)&Cr[0 * 4352 + row * 68 + cc];
        f32x4 s1 = *(const f32x4*)&Cr[1 * 4352 + row * 68 + cc];
        f32x4 s2 = *(const f32x4*)&Cr[2 * 4352 + row * 68 + cc];
        f32x4 s3 = *(const f32x4*)&Cr[3 * 4352 + row * 68 + cc];
        f32x4 v = (s0 + s1) + (s2 + s3) + bv4;
        if (sp) {
            v[0] = softplus_f(v[0]); v[1] = softplus_f(v[1]);
            v[2] = softplus_f(v[2]); v[3] = softplus_f(v[3]);
        }
        *(f32x4*)&dst[(size_t)(m_base + row) * 1024 + n_base + cc] = v;
    }
}

__global__ __launch_bounds__(256) void feat_kernel(const float* __restrict__ Km,
                                                   const float* __restrict__ Kv,
                                                   bf16_t* __restrict__ Gbf,
                                                   float* __restrict__ cvec) {
    const int h = blockIdx.x, kb = blockIdx.y;
    const int t = threadIdx.x;
    const int kx = t & 63;
    const int dg = t >> 6;
    const int katt = kb * 64 + kx;
    const float* kvp = Kv + (size_t)katt * 1024 + h * 64 + dg * 16;
    const float* kmp = Km + (size_t)katt * 1024 + h * 64 + dg * 16;
    bf16_t* grow = Gbf + ((size_t)(h * 256 + katt)) * 128;
    float cp = 0.f;
#pragma unroll
    for (int c = 0; c < 4; ++c) {
        f32x4 kv = *(const f32x4*)(kvp + c * 4);
        f32x4 km = *(const f32x4*)(kmp + c * 4);
        bf16x4 o1, o2;
#pragma unroll
        for (int e = 0; e < 4; ++e) {
            const float r = 0.5f * fast_rcp(kv[e]);
            o1[e] = (bf16_t)r;
            o2[e] = (bf16_t)(-2.f * km[e] * r);
            cp += km[e] * km[e] * r + 0.5f * __logf(kv[e]);
        }
        *(bf16x4*)&grow[dg * 16 + c * 4]      = o1;
        *(bf16x4*)&grow[64 + dg * 16 + c * 4] = o2;
    }
    __shared__ float red[4][64];
    red[dg][kx] = cp;
    __syncthreads();
    if (dg == 0)
        cvec[h * 256 + katt] = red[0][kx] + red[1][kx] + red[2][kx] + red[3][kx];
}

__global__ __launch_bounds__(512) void attn_v7(const float* __restrict__ Qm,
                                               const float* __restrict__ Qv,
                                               const bf16_t* __restrict__ Gbf,
                                               const float* __restrict__ cvec,
                                               const float* __restrict__ Vm,
                                               const float* __restrict__ Vv,
                                               bf16_t* __restrict__ Omu,
                                               bf16_t* __restrict__ Ovar) {
    __shared__ __align__(16) unsigned char smem[ATTN_SMEM];
    attn_body(smem, threadIdx.x, blockIdx.x, blockIdx.y, Qm, Qv, Gbf, cvec, Vm, Vv, Omu, Ovar);
}

// ---------------- launch ----------------
extern "C" void kernel_launch(void* const* d_in, const int* in_sizes, int n_in,
                              void* d_out, int out_size, void* d_ws, size_t ws_size,
                              hipStream_t stream) {
    const float* mu  = (const float*)d_in[0];
    const float* var = (const float*)d_in[1];
    uint8_t* ws = (uint8_t*)d_ws;

    // ---- fused cooperative path ----
    FusedArgs fa;
    fa.mu = mu; fa.var = var;
    for (int i = 0; i < 8; ++i) {
        fa.W[i]    = (const float*)d_in[2 + 2 * i];
        fa.Bias[i] = (const float*)d_in[3 + 2 * i];
    }
    fa.WtB  = (bf16_t*)(ws);                       // 16 MB
    fa.Proj = (float*)(ws + (16u << 20));          // 4 MB (Qm,Qv,Vm,Vv)
    fa.Obm  = (bf16_t*)(ws + (20u << 20));         // 512 KB
    fa.Obv  = (bf16_t*)(ws + (20u << 20) + (512u << 10));
    fa.Gbf  = (bf16_t*)(ws + (21u << 20));         // 1 MB
    fa.cvec = (float*)(ws + (22u << 20));          // 16 KB
    fa.out_mu  = (float*)d_out;
    fa.out_var = (float*)d_out + 262144;

    void* kp[] = { &fa };
    hipError_t err = hipLaunchCooperativeKernel((void*)fused_all, dim3(256), dim3(512),
                                                kp, 0, stream);
    if (err == hipSuccess) return;
    (void)hipGetLastError();   // clear, fall back to verified 5-kernel path

    // ---- legacy fallback (identical to previous best) ----
    bf16_t* Abf_mu  = (bf16_t*)(ws);
    bf16_t* Abf_var = (bf16_t*)(ws + (512u << 10));
    bf16_t* WtB     = (bf16_t*)(ws + (1u << 20));
    float*  Proj    = (float*)(ws + (17u << 20));
    bf16_t* Obf_mu  = (bf16_t*)(ws + (23u << 20));
    bf16_t* Obf_var = (bf16_t*)(ws + (23u << 20) + (512u << 10));
    bf16_t* Gbf     = (bf16_t*)(ws + (24u << 20));
    float*  cvec    = (float*)(ws + (25u << 20));

    PrepArgs pa;
    for (int i = 0; i < 8; ++i) pa.src[i] = (const float*)d_in[2 + 2 * i];
    pa.mu = mu; pa.var = var;
    prep_kernel<<<dim3(16, 16, 9), 256, 0, stream>>>(pa, WtB, Abf_mu, Abf_var);

    GemmArgs g1;
    for (int z = 0; z < 6; ++z) {
        g1.A[z]    = (z & 1) ? Abf_var : Abf_mu;
        g1.Wt[z]   = WtB + (size_t)z * 1048576;
        g1.bias[z] = (const float*)d_in[3 + 2 * z];
        g1.dst[z]  = Proj + (size_t)z * 262144;
        g1.splus[z] = (z & 1);
    }
    gemm_splitk<<<dim3(16, 4, 6), 256, 0, stream>>>(g1);

    feat_kernel<<<dim3(16, 4), 256, 0, stream>>>(Proj + 2 * 262144, Proj + 3 * 262144, Gbf, cvec);

    attn_v7<<<dim3(16, 16), 512, 0, stream>>>(Proj, Proj + 262144, Gbf, cvec,
                                              Proj + 4 * 262144, Proj + 5 * 262144,
                                              Obf_mu, Obf_var);

    GemmArgs g3;
    for (int z = 0; z < 6; ++z) {
        g3.A[z]    = Obf_mu;
        g3.Wt[z]   = WtB + (size_t)6 * 1048576;
        g3.bias[z] = (const float*)d_in[15];
        g3.dst[z]  = (float*)d_out;
        g3.splus[z] = 0;
    }
    g3.A[1]    = Obf_var;
    g3.Wt[1]   = WtB + (size_t)7 * 1048576;
    g3.bias[1] = (const float*)d_in[17];
    g3.dst[1]  = (float*)d_out + 262144;
    g3.splus[1] = 1;
    gemm_splitk<<<dim3(16, 4, 2), 256, 0, stream>>>(g3);
}

// Round 2
// 150.756 us; speedup vs baseline: 2.6273x; 2.6273x over previous
//
#include <hip/hip_runtime.h>
#include <math.h>

typedef __bf16 bf16_t;
typedef bf16_t bf16x4 __attribute__((ext_vector_type(4)));
typedef bf16_t bf16x8 __attribute__((ext_vector_type(8)));
typedef float  f32x4  __attribute__((ext_vector_type(4)));

__device__ __forceinline__ float softplus_f(float x) {
    return (x > 20.f) ? x : log1pf(expf(x));
}

__device__ __forceinline__ float fast_rcp(float x) {
#if __has_builtin(__builtin_amdgcn_rcpf)
    return __builtin_amdgcn_rcpf(x);
#else
    return 1.0f / x;
#endif
}

// ============================================================================
// prep: weight transpose+convert only (activations consumed as f32 by GEMM now)
// ============================================================================
struct PrepArgs { const float* src[8]; };

__global__ __launch_bounds__(256) void prep_kernel(PrepArgs pa, bf16_t* __restrict__ wtbase) {
    const int t = threadIdx.x;
    const int kt = blockIdx.x, nt = blockIdx.y, wm = blockIdx.z;
    const float* __restrict__ W = pa.src[wm];
    bf16_t* __restrict__ Wt = wtbase + (size_t)wm * 1048576;
    __shared__ bf16_t Ts[64][72];
    const int r0 = t >> 4, c4 = (t & 15) * 4;
#pragma unroll
    for (int rep = 0; rep < 4; ++rep) {
        const int r = r0 + rep * 16;
        const float4 v = *(const float4*)&W[(size_t)(kt * 64 + r) * 1024 + nt * 64 + c4];
        Ts[c4 + 0][r] = (bf16_t)v.x;
        Ts[c4 + 1][r] = (bf16_t)v.y;
        Ts[c4 + 2][r] = (bf16_t)v.z;
        Ts[c4 + 3][r] = (bf16_t)v.w;
    }
    __syncthreads();
#pragma unroll
    for (int rep = 0; rep < 2; ++rep) {
        const int chunk = t + rep * 256;
        const int n = chunk >> 3, kc = (chunk & 7) * 8;
        bf16x8 v = *(const bf16x8*)&Ts[n][kc];
        *(bf16x8*)&Wt[(size_t)(nt * 64 + n) * 1024 + kt * 64 + kc] = v;
    }
}

// ============================================================================
// 4-wave 64x64-tile GEMM core (verified legacy gemm_splitk structure).
// Wave w owns K slice [w*256, +256) in 4 sub-slices of 64, register prefetch.
// AF32: A is f32, converted to bf16 at LDS-write (verified in round-1 fused run).
// Returns raw sums: out[i] = rows (t>>4)+i*16, cols (t&15)*4..+3 (no bias).
// Wave-private LDS staging (no barrier needed inside the K loop).
// ============================================================================
template<bool AF32>
__device__ __forceinline__ void gemm4_core(const void* Aptr, const bf16_t* __restrict__ Wt,
                                           const int m_base, const int n_base,
                                           unsigned char* smem, const int t, f32x4 out[4]) {
    __syncthreads();   // smem handoff from any previous use (epilogue reads of Cr)
    bf16_t* stage = (bf16_t*)smem;
    float*  Cr    = (float*)smem;
    const int lane = t & 63, w = t >> 6;
    bf16_t* As = stage + w * 9216;
    bf16_t* Bs = As + 4608;
    const int r8 = lane >> 3, kb = lane & 7;
    const int fr = lane & 15, fq = lane >> 4, fk = fq * 8;

    const bf16_t* Bb = Wt + (size_t)n_base * 1024 + w * 256 + kb * 8;
    const float*  Af = (const float*)Aptr  + (size_t)m_base * 1024 + w * 256 + kb * 8;
    const bf16_t* Ab = (const bf16_t*)Aptr + (size_t)m_base * 1024 + w * 256 + kb * 8;

    f32x4 acc[4][4] = {};
    bf16x8 pa[8], pb[8];
    f32x4 paf0[8], paf1[8];
#pragma unroll
    for (int i = 0; i < 8; ++i) {
        pb[i] = *(const bf16x8*)(Bb + (size_t)(i * 8 + r8) * 1024);
        if constexpr (AF32) {
            paf0[i] = *(const f32x4*)(Af + (size_t)(i * 8 + r8) * 1024);
            paf1[i] = *(const f32x4*)(Af + (size_t)(i * 8 + r8) * 1024 + 4);
        } else {
            pa[i] = *(const bf16x8*)(Ab + (size_t)(i * 8 + r8) * 1024);
        }
    }

#pragma unroll
    for (int s = 0; s < 4; ++s) {
#pragma unroll
        for (int i = 0; i < 8; ++i) {
            bf16x8 av;
            if constexpr (AF32) {
#pragma unroll
                for (int e = 0; e < 4; ++e) {
                    av[e]     = (bf16_t)paf0[i][e];
                    av[e + 4] = (bf16_t)paf1[i][e];
                }
            } else {
                av = pa[i];
            }
            *(bf16x8*)&As[(i * 8 + r8) * 72 + kb * 8] = av;
            *(bf16x8*)&Bs[(i * 8 + r8) * 72 + kb * 8] = pb[i];
        }
        if (s < 3) {   // issue next slice's loads; in flight during MFMA below
            const int off = (s + 1) * 64;
#pragma unroll
            for (int i = 0; i < 8; ++i) {
                pb[i] = *(const bf16x8*)(Bb + (size_t)(i * 8 + r8) * 1024 + off);
                if constexpr (AF32) {
                    paf0[i] = *(const f32x4*)(Af + (size_t)(i * 8 + r8) * 1024 + off);
                    paf1[i] = *(const f32x4*)(Af + (size_t)(i * 8 + r8) * 1024 + off + 4);
                } else {
                    pa[i] = *(const bf16x8*)(Ab + (size_t)(i * 8 + r8) * 1024 + off);
                }
            }
        }
#pragma unroll
        for (int kh = 0; kh < 2; ++kh) {
            bf16x8 aF[4], bF[4];
#pragma unroll
            for (int i = 0; i < 4; ++i)
                aF[i] = *(const bf16x8*)&As[(i * 16 + fr) * 72 + kh * 32 + fk];
#pragma unroll
            for (int j = 0; j < 4; ++j)
                bF[j] = *(const bf16x8*)&Bs[(j * 16 + fr) * 72 + kh * 32 + fk];
#pragma unroll
            for (int i = 0; i < 4; ++i)
#pragma unroll
                for (int j = 0; j < 4; ++j)
                    acc[i][j] = __builtin_amdgcn_mfma_f32_16x16x32_bf16(aF[i], bF[j], acc[i][j], 0, 0, 0);
        }
    }

    __syncthreads();
    {
        float* Crw = Cr + w * 4352;
        const int orow = fq * 4;
#pragma unroll
        for (int i = 0; i < 4; ++i)
#pragma unroll
            for (int j = 0; j < 4; ++j)
#pragma unroll
                for (int rr = 0; rr < 4; ++rr)
                    Crw[(i * 16 + orow + rr) * 68 + j * 16 + fr] = acc[i][j][rr];
    }
    __syncthreads();

    const int cc = (t & 15) * 4;
#pragma unroll
    for (int i = 0; i < 4; ++i) {
        const int row = (t >> 4) + i * 16;
        f32x4 s0 = *(const f32x4*)&Cr[0 * 4352 + row * 68 + cc];
        f32x4 s1 = *(const f32x4*)&Cr[1 * 4352 + row * 68 + cc];
        f32x4 s2 = *(const f32x4*)&Cr[2 * 4352 + row * 68 + cc];
        f32x4 s3 = *(const f32x4*)&Cr[3 * 4352 + row * 68 + cc];
        out[i] = (s0 + s1) + (s2 + s3);
    }
}

// ============================================================================
// proj: z in {0:Qm, 1:Qv, 2:K-fused(feat), 3:Vm, 4:Vv}; grid (16 n, 4 m, 5)
// Proj slots: 0 Qm, 1 Qv, 2 Vm, 3 Vv. K-fused emits Gbf/cvec directly.
// ============================================================================
struct ProjArgs {
    const float* mu; const float* var;
    const bf16_t* WtB;
    const float* bias[6];   // q_mu, q_var, k_mu, k_var, v_mu, v_var
    float* Proj;
    bf16_t* Gbf; float* cvec;
};

__global__ __launch_bounds__(256, 2) void proj_kernel(ProjArgs a) {
    __shared__ __align__(16) unsigned char smem[73728];
    const int z = blockIdx.z;
    const int nb = blockIdx.x * 64, mb = blockIdx.y * 64;
    const int t = threadIdx.x;
    const int cc = (t & 15) * 4;

    if (z != 2) {
        const int wi   = (z < 2) ? z : (z + 1);       // 0,1,4,5
        const int slot = (z < 2) ? z : (z - 1);       // 0,1,2,3
        const int sp   = (z == 1) || (z == 4);
        const void* A  = (z == 1 || z == 4) ? (const void*)a.var : (const void*)a.mu;
        f32x4 o[4];
        gemm4_core<true>(A, a.WtB + (size_t)wi * 1048576, mb, nb, smem, t, o);
        const f32x4 bv = *(const f32x4*)&a.bias[wi][nb + cc];
        float* dst = a.Proj + (size_t)slot * 262144;
#pragma unroll
        for (int i = 0; i < 4; ++i) {
            const int row = (t >> 4) + i * 16;
            f32x4 v = o[i] + bv;
            if (sp) {
                v[0] = softplus_f(v[0]); v[1] = softplus_f(v[1]);
                v[2] = softplus_f(v[2]); v[3] = softplus_f(v[3]);
            }
            *(f32x4*)&dst[(size_t)(mb + row) * 1024 + nb + cc] = v;
        }
    } else {
        // K projection (Km and Kv tiles) + feat epilogue; Km/Kv never hit HBM
        const int h = blockIdx.x;   // n-tile == head (64 cols per head)
        f32x4 okm[4], okv[4];
        gemm4_core<true>(a.mu,  a.WtB + (size_t)2 * 1048576, mb, nb, smem, t, okm);
        gemm4_core<true>(a.var, a.WtB + (size_t)3 * 1048576, mb, nb, smem, t, okv);
        const f32x4 bkm = *(const f32x4*)&a.bias[2][nb + cc];
        const f32x4 bkv = *(const f32x4*)&a.bias[3][nb + cc];
#pragma unroll
        for (int i = 0; i < 4; ++i) {
            const int row = (t >> 4) + i * 16;
            const int katt = mb + row;
            const f32x4 km  = okm[i] + bkm;
            const f32x4 kvr = okv[i] + bkv;
            bf16x4 o1, o2;
            float c = 0.f;
#pragma unroll
            for (int e = 0; e < 4; ++e) {
                const float kv = softplus_f(kvr[e]);
                const float r  = 0.5f * fast_rcp(kv);
                o1[e] = (bf16_t)r;
                o2[e] = (bf16_t)(-2.f * km[e] * r);
                c += km[e] * km[e] * r + 0.5f * __logf(kv);
            }
            bf16_t* grow = a.Gbf + ((size_t)(h * 256 + katt)) * 128;
            *(bf16x4*)&grow[cc]      = o1;
            *(bf16x4*)&grow[64 + cc] = o2;
            // reduce c across the 16 threads sharing this row (lanes grouped by 16)
#pragma unroll
            for (int off = 8; off > 0; off >>= 1)
                c += __shfl_xor(c, off, 16);
            if ((t & 15) == 0)
                a.cvec[h * 256 + katt] = c;
        }
    }
}

// ============================================================================
// attention (verified attn_v7 structure)
// ============================================================================
#define OFF_VM   0
#define OFF_VV   36864
#define OFF_FS   73728
#define OFF_SC   82176
#define OFF_PHI  98816
#define OFF_PLO  107264
#define OFF_P2H  115712
#define OFF_P2L  124160
#define ATTN_SMEM 132608

__global__ __launch_bounds__(512) void attn_v7(const float* __restrict__ Qm,
                                               const float* __restrict__ Qv,
                                               const bf16_t* __restrict__ Gbf,
                                               const float* __restrict__ cvec,
                                               const float* __restrict__ Vm,
                                               const float* __restrict__ Vv,
                                               bf16_t* __restrict__ Omu,
                                               bf16_t* __restrict__ Ovar) {
    __shared__ __align__(16) unsigned char smem[ATTN_SMEM];
    bf16_t* Vsm = (bf16_t*)(smem + OFF_VM);   // [256][72] bf16
    bf16_t* Vsv = (bf16_t*)(smem + OFF_VV);
    float*  Fs  = (float*)(smem + OFF_FS);    // [16][132] f32
    float*  Sc  = (float*)(smem + OFF_SC);    // [16][260] f32
    bf16_t* Phi = (bf16_t*)(smem + OFF_PHI);  // [16][264] bf16
    bf16_t* Plo = (bf16_t*)(smem + OFF_PLO);
    bf16_t* P2h = (bf16_t*)(smem + OFF_P2H);
    bf16_t* P2l = (bf16_t*)(smem + OFF_P2L);

    const int qt = blockIdx.x, h = blockIdx.y;
    const int t = threadIdx.x, w = t >> 6, lane = t & 63;
    const int fr = lane & 15, fq = lane >> 4;
    const int n0 = w * 32;

    const bf16_t* gB = Gbf + ((size_t)(h * 256 + n0 + fr)) * 128 + fq * 8;

    bf16x8 bcur[4];
#pragma unroll
    for (int ks = 0; ks < 4; ++ks) bcur[ks] = *(const bf16x8*)(gB + ks * 32);

    if (t < 256) {
        const int r = t >> 4, c = t & 15;
        f32x4 qm = *(const f32x4*)(Qm + (size_t)(qt * 16 + r) * 1024 + h * 64 + c * 4);
        f32x4 qv = *(const f32x4*)(Qv + (size_t)(qt * 16 + r) * 1024 + h * 64 + c * 4);
        *(f32x4*)&Fs[r * 132 + c * 4]      = qm * qm + qv;
        *(f32x4*)&Fs[r * 132 + 64 + c * 4] = qm;
    }
    __syncthreads();

    bf16x8 ahi[4], alo[4];
#pragma unroll
    for (int ks = 0; ks < 4; ++ks) {
        f32x4 f0 = *(const f32x4*)&Fs[fr * 132 + ks * 32 + fq * 8];
        f32x4 f1 = *(const f32x4*)&Fs[fr * 132 + ks * 32 + fq * 8 + 4];
#pragma unroll
        for (int e = 0; e < 4; ++e) {
            bf16_t hb = (bf16_t)f0[e];
            ahi[ks][e] = hb; alo[ks][e] = (bf16_t)(f0[e] - (float)hb);
            bf16_t hb2 = (bf16_t)f1[e];
            ahi[ks][e + 4] = hb2; alo[ks][e + 4] = (bf16_t)(f1[e] - (float)hb2);
        }
    }

    const int tm = t & 255;
    const int vk = tm >> 2, vpart = tm & 3;
    const float* Vsrc = (t >= 256) ? Vv : Vm;
    bf16_t*      Vdst = (t >= 256) ? Vsv : Vsm;

#pragma unroll
    for (int nt = 0; nt < 2; ++nt) {
        const int ra = vk + (2 * nt) * 64;
        const int rb = vk + (2 * nt + 1) * 64;
        const float* vsa = Vsrc + (size_t)ra * 1024 + h * 64 + vpart * 16;
        const float* vsb = Vsrc + (size_t)rb * 1024 + h * 64 + vpart * 16;
        f32x4 va0 = *(const f32x4*)(vsa),     va1 = *(const f32x4*)(vsa + 4);
        f32x4 va2 = *(const f32x4*)(vsa + 8), va3 = *(const f32x4*)(vsa + 12);
        f32x4 vb0 = *(const f32x4*)(vsb),     vb1 = *(const f32x4*)(vsb + 4);
        f32x4 vb2 = *(const f32x4*)(vsb + 8), vb3 = *(const f32x4*)(vsb + 12);

        bf16x8 bnxt[4];
        if (nt < 1) {
#pragma unroll
            for (int ks = 0; ks < 4; ++ks)
                bnxt[ks] = *(const bf16x8*)(gB + 2048 + ks * 32);
        }

        f32x4 acc = {0.f, 0.f, 0.f, 0.f};
#pragma unroll
        for (int ks = 0; ks < 4; ++ks) {
            acc = __builtin_amdgcn_mfma_f32_16x16x32_bf16(ahi[ks], bcur[ks], acc, 0, 0, 0);
            acc = __builtin_amdgcn_mfma_f32_16x16x32_bf16(alo[ks], bcur[ks], acc, 0, 0, 0);
        }

        {
            bf16_t* da = Vdst + ra * 72 + vpart * 16;
            bf16_t* db = Vdst + rb * 72 + vpart * 16;
            bf16x8 o0, o1;
            o0[0]=(bf16_t)va0[0]; o0[1]=(bf16_t)va0[1]; o0[2]=(bf16_t)va0[2]; o0[3]=(bf16_t)va0[3];
            o0[4]=(bf16_t)va1[0]; o0[5]=(bf16_t)va1[1]; o0[6]=(bf16_t)va1[2]; o0[7]=(bf16_t)va1[3];
            o1[0]=(bf16_t)va2[0]; o1[1]=(bf16_t)va2[1]; o1[2]=(bf16_t)va2[2]; o1[3]=(bf16_t)va2[3];
            o1[4]=(bf16_t)va3[0]; o1[5]=(bf16_t)va3[1]; o1[6]=(bf16_t)va3[2]; o1[7]=(bf16_t)va3[3];
            *(bf16x8*)(da)     = o0;
            *(bf16x8*)(da + 8) = o1;
            o0[0]=(bf16_t)vb0[0]; o0[1]=(bf16_t)vb0[1]; o0[2]=(bf16_t)vb0[2]; o0[3]=(bf16_t)vb0[3];
            o0[4]=(bf16_t)vb1[0]; o0[5]=(bf16_t)vb1[1]; o0[6]=(bf16_t)vb1[2]; o0[7]=(bf16_t)vb1[3];
            o1[0]=(bf16_t)vb2[0]; o1[1]=(bf16_t)vb2[1]; o1[2]=(bf16_t)vb2[2]; o1[3]=(bf16_t)vb2[3];
            o1[4]=(bf16_t)vb3[0]; o1[5]=(bf16_t)vb3[1]; o1[6]=(bf16_t)vb3[2]; o1[7]=(bf16_t)vb3[3];
            *(bf16x8*)(db)     = o0;
            *(bf16x8*)(db + 8) = o1;
        }

        const float cv = cvec[h * 256 + n0 + nt * 16 + fr];
        f32x4 lg = (acc + cv) * (-0.125f);
#pragma unroll
        for (int reg = 0; reg < 4; ++reg)
            Sc[(fq * 4 + reg) * 260 + n0 + nt * 16 + fr] = lg[reg];

#pragma unroll
        for (int ks = 0; ks < 4; ++ks) bcur[ks] = bnxt[ks];
    }
    __syncthreads();

    const int fw = w * 2;
    f32x4 sr[2];
#pragma unroll
    for (int r = 0; r < 2; ++r)
        sr[r] = *(const f32x4*)&Sc[(fw + r) * 260 + lane * 4];
#pragma unroll
    for (int r = 0; r < 2; ++r) {
        f32x4 s = sr[r];
        float mloc = fmaxf(fmaxf(s[0], s[1]), fmaxf(s[2], s[3]));
#pragma unroll
        for (int off = 32; off > 0; off >>= 1)
            mloc = fmaxf(mloc, __shfl_xor(mloc, off, 64));
        s[0] = __expf(s[0] - mloc); s[1] = __expf(s[1] - mloc);
        s[2] = __expf(s[2] - mloc); s[3] = __expf(s[3] - mloc);
        float sl = (s[0] + s[1]) + (s[2] + s[3]);
#pragma unroll
        for (int off = 32; off > 0; off >>= 1)
            sl += __shfl_xor(sl, off, 64);
        sr[r] = s * fast_rcp(sl);
    }

#pragma unroll
    for (int r = 0; r < 2; ++r) {
        bf16x4 phi, plo, p2hi, p2lo;
#pragma unroll
        for (int e = 0; e < 4; ++e) {
            const float p = sr[r][e];
            const bf16_t hb = (bf16_t)p;
            phi[e] = hb; plo[e] = (bf16_t)(p - (float)hb);
            const float p2 = p * p;
            const bf16_t h2 = (bf16_t)p2;
            p2hi[e] = h2; p2lo[e] = (bf16_t)(p2 - (float)h2);
        }
        const int row = fw + r;
        *(bf16x4*)&Phi[row * 264 + lane * 4] = phi;
        *(bf16x4*)&Plo[row * 264 + lane * 4] = plo;
        *(bf16x4*)&P2h[row * 264 + lane * 4] = p2hi;
        *(bf16x4*)&P2l[row * 264 + lane * 4] = p2lo;
    }
    __syncthreads();

    const int tile = w & 3;
    const int isvar = w >> 2;
    const bf16_t* Pa = isvar ? P2h : Phi;
    const bf16_t* Pb = isvar ? P2l : Plo;
    const bf16_t* Vs = isvar ? Vsv : Vsm;
    f32x4 accp = {0.f, 0.f, 0.f, 0.f};
#pragma unroll
    for (int k0 = 0; k0 < 256; k0 += 32) {
        const int ka = k0 + fq * 8;
        bf16x8 a1 = *(const bf16x8*)&Pa[fr * 264 + ka];
        bf16x8 a2 = *(const bf16x8*)&Pb[fr * 264 + ka];
        bf16x8 bfr;
#pragma unroll
        for (int j = 0; j < 8; ++j)
            bfr[j] = Vs[(ka + j) * 72 + tile * 16 + fr];
        accp = __builtin_amdgcn_mfma_f32_16x16x32_bf16(a1, bfr, accp, 0, 0, 0);
        accp = __builtin_amdgcn_mfma_f32_16x16x32_bf16(a2, bfr, accp, 0, 0, 0);
    }

    bf16_t* Out = isvar ? Ovar : Omu;
#pragma unroll
    for (int reg = 0; reg < 4; ++reg) {
        const int qg = qt * 16 + fq * 4 + reg;
        const size_t ob = (size_t)qg * 1024 + h * 64 + tile * 16 + fr;
        Out[ob] = (bf16_t)accp[reg];
    }
}

// ============================================================================
// output projection (verified legacy gemm_splitk, bf16 A)
// ============================================================================
struct OutArgs {
    const bf16_t* A[2];
    const bf16_t* Wt[2];
    const float*  bias[2];
    float*        dst[2];
    int           splus[2];
};

__global__ __launch_bounds__(256, 2) void out_gemm(OutArgs args) {
    const int z = blockIdx.z;
    const bf16_t* __restrict__ A    = args.A[z];
    const bf16_t* __restrict__ Wt   = args.Wt[z];
    const float*  __restrict__ bias = args.bias[z];
    float*        __restrict__ dst  = args.dst[z];
    const int sp = args.splus[z];

    const int n_base = blockIdx.x * 64;
    const int m_base = blockIdx.y * 64;

    __shared__ __align__(16) unsigned char smem[73728];
    const int t = threadIdx.x;
    f32x4 o[4];
    gemm4_core<false>(A, Wt, m_base, n_base, smem, t, o);

    const int cc = (t & 15) * 4;
    const f32x4 bv = *(const f32x4*)&bias[n_base + cc];
#pragma unroll
    for (int i = 0; i < 4; ++i) {
        const int row = (t >> 4) + i * 16;
        f32x4 v = o[i] + bv;
        if (sp) {
            v[0] = softplus_f(v[0]); v[1] = softplus_f(v[1]);
            v[2] = softplus_f(v[2]); v[3] = softplus_f(v[3]);
        }
        *(f32x4*)&dst[(size_t)(m_base + row) * 1024 + n_base + cc] = v;
    }
}

// ---------------- launch ----------------
extern "C" void kernel_launch(void* const* d_in, const int* in_sizes, int n_in,
                              void* d_out, int out_size, void* d_ws, size_t ws_size,
                              hipStream_t stream) {
    const float* mu  = (const float*)d_in[0];
    const float* var = (const float*)d_in[1];
    uint8_t* ws = (uint8_t*)d_ws;

    bf16_t* WtB  = (bf16_t*)(ws);                              // 8 x 2 MB
    float*  Proj = (float*)(ws + (16u << 20));                 // 4 x 1 MB: Qm, Qv, Vm, Vv
    bf16_t* Obm  = (bf16_t*)(ws + (20u << 20));                // 512 KB
    bf16_t* Obv  = (bf16_t*)(ws + (20u << 20) + (512u << 10)); // 512 KB
    bf16_t* Gbf  = (bf16_t*)(ws + (21u << 20));                // 1 MB
    float*  cvec = (float*)(ws + (22u << 20));                 // 16 KB

    // 1) weight transpose+convert
    PrepArgs pa;
    for (int i = 0; i < 8; ++i) pa.src[i] = (const float*)d_in[2 + 2 * i];
    prep_kernel<<<dim3(16, 16, 8), 256, 0, stream>>>(pa, WtB);

    // 2) projections; K fused with feat (Km/Kv never materialized)
    ProjArgs pr;
    pr.mu = mu; pr.var = var; pr.WtB = WtB;
    for (int i = 0; i < 6; ++i) pr.bias[i] = (const float*)d_in[3 + 2 * i];
    pr.Proj = Proj; pr.Gbf = Gbf; pr.cvec = cvec;
    proj_kernel<<<dim3(16, 4, 5), 256, 0, stream>>>(pr);

    // 3) attention
    attn_v7<<<dim3(16, 16), 512, 0, stream>>>(Proj, Proj + 262144, Gbf, cvec,
                                              Proj + 2 * 262144, Proj + 3 * 262144,
                                              Obm, Obv);

    // 4) output projections
    OutArgs g3;
    g3.A[0] = Obm;  g3.Wt[0] = WtB + (size_t)6 * 1048576;
    g3.bias[0] = (const float*)d_in[15];
    g3.dst[0] = (float*)d_out;             g3.splus[0] = 0;
    g3.A[1] = Obv;  g3.Wt[1] = WtB + (size_t)7 * 1048576;
    g3.bias[1] = (const float*)d_in[17];
    g3.dst[1] = (float*)d_out + 262144;    g3.splus[1] = 1;
    out_gemm<<<dim3(16, 4, 2), 256, 0, stream>>>(g3);
}

// Round 3
// 148.529 us; speedup vs baseline: 2.6667x; 1.0150x over previous
//
#include <hip/hip_runtime.h>
#include <math.h>

typedef __bf16 bf16_t;
typedef bf16_t bf16x4 __attribute__((ext_vector_type(4)));
typedef bf16_t bf16x8 __attribute__((ext_vector_type(8)));
typedef float  f32x4  __attribute__((ext_vector_type(4)));

__device__ __forceinline__ float softplus_f(float x) {
    return (x > 20.f) ? x : log1pf(expf(x));
}

__device__ __forceinline__ float fast_rcp(float x) {
#if __has_builtin(__builtin_amdgcn_rcpf)
    return __builtin_amdgcn_rcpf(x);
#else
    return 1.0f / x;
#endif
}

// ============================================================================
// 4-wave 64x64-tile GEMM core with ON-THE-FLY B TRANSPOSE (no prep kernel).
// B source is W in original f32 [k][n] layout. Per wave-slice (64k x 64n):
//   load 16x f32x4 coalesced along n (lane: rows fq*16+0..15, cols fr*4..+3),
//   pack transposed -> 8x ds_write_b128 into the VERIFIED Bs[n][72k] layout
//   (2-way bank aliasing only, which is free on gfx950).
// Fragment reads and MFMA loop are byte-identical to the verified core.
// A path: AF32 (f32 activations, convert at LDS write) or bf16 — both verified.
// Returns raw split-K sums: out[i] = rows (t>>4)+i*16, cols (t&15)*4..+3.
// ============================================================================
template<bool AF32>
__device__ __forceinline__ void gemmT_core(const void* Aptr, const float* __restrict__ Wf,
                                           const int m_base, const int n_base,
                                           unsigned char* smem, const int t, f32x4 out[4]) {
    __syncthreads();   // smem handoff from any previous use (epilogue reads of Cr)
    bf16_t* stage = (bf16_t*)smem;
    float*  Cr    = (float*)smem;
    const int lane = t & 63, w = t >> 6;
    bf16_t* As = stage + w * 9216;
    bf16_t* Bs = As + 4608;
    const int r8 = lane >> 3, kb = lane & 7;
    const int fr = lane & 15, fq = lane >> 4, fk = fq * 8;
    const int bc = fr;             // n-chunk (4 cols)
    const int br16 = fq * 16;      // k-row base (16 rows)

    const float*  Af = (const float*)Aptr  + (size_t)m_base * 1024 + w * 256 + kb * 8;
    const bf16_t* Ab = (const bf16_t*)Aptr + (size_t)m_base * 1024 + w * 256 + kb * 8;
    const float*  Bf = Wf + (size_t)(w * 256 + br16) * 1024 + n_base + bc * 4;

    f32x4 acc[4][4] = {};
    bf16x8 pa[8];
    f32x4 paf0[8], paf1[8];
    f32x4 pbf[16];

    // prologue: prefetch slice 0 (A and B) into registers
#pragma unroll
    for (int i = 0; i < 8; ++i) {
        if constexpr (AF32) {
            paf0[i] = *(const f32x4*)(Af + (size_t)(i * 8 + r8) * 1024);
            paf1[i] = *(const f32x4*)(Af + (size_t)(i * 8 + r8) * 1024 + 4);
        } else {
            pa[i] = *(const bf16x8*)(Ab + (size_t)(i * 8 + r8) * 1024);
        }
    }
#pragma unroll
    for (int i = 0; i < 16; ++i)
        pbf[i] = *(const f32x4*)(Bf + (size_t)i * 1024);

#pragma unroll
    for (int s = 0; s < 4; ++s) {
        // ---- write A slice to LDS (verified layout) ----
#pragma unroll
        for (int i = 0; i < 8; ++i) {
            bf16x8 av;
            if constexpr (AF32) {
#pragma unroll
                for (int e = 0; e < 4; ++e) {
                    av[e]     = (bf16_t)paf0[i][e];
                    av[e + 4] = (bf16_t)paf1[i][e];
                }
            } else {
                av = pa[i];
            }
            *(bf16x8*)&As[(i * 8 + r8) * 72 + kb * 8] = av;
        }
        // ---- write B slice transposed to LDS (verified Bs[n][72k] layout) ----
        // pbf[i] holds W[k0 + br16 + i][n_base + bc*4 .. +3]
#pragma unroll
        for (int e = 0; e < 4; ++e) {
            bf16x8 lo, hi;
#pragma unroll
            for (int q = 0; q < 8; ++q) {
                lo[q] = (bf16_t)pbf[q][e];
                hi[q] = (bf16_t)pbf[q + 8][e];
            }
            *(bf16x8*)&Bs[(bc * 4 + e) * 72 + br16]     = lo;
            *(bf16x8*)&Bs[(bc * 4 + e) * 72 + br16 + 8] = hi;
        }
        if (s < 3) {   // issue next slice's loads; in flight during MFMA below
            const int off = (s + 1) * 64;
#pragma unroll
            for (int i = 0; i < 8; ++i) {
                if constexpr (AF32) {
                    paf0[i] = *(const f32x4*)(Af + (size_t)(i * 8 + r8) * 1024 + off);
                    paf1[i] = *(const f32x4*)(Af + (size_t)(i * 8 + r8) * 1024 + off + 4);
                } else {
                    pa[i] = *(const bf16x8*)(Ab + (size_t)(i * 8 + r8) * 1024 + off);
                }
            }
#pragma unroll
            for (int i = 0; i < 16; ++i)
                pbf[i] = *(const f32x4*)(Bf + (size_t)i * 1024 + (size_t)off * 1024);
        }
        // ---- MFMA on current slice (verified, unchanged) ----
#pragma unroll
        for (int kh = 0; kh < 2; ++kh) {
            bf16x8 aF[4], bF[4];
#pragma unroll
            for (int i = 0; i < 4; ++i)
                aF[i] = *(const bf16x8*)&As[(i * 16 + fr) * 72 + kh * 32 + fk];
#pragma unroll
            for (int j = 0; j < 4; ++j)
                bF[j] = *(const bf16x8*)&Bs[(j * 16 + fr) * 72 + kh * 32 + fk];
#pragma unroll
            for (int i = 0; i < 4; ++i)
#pragma unroll
                for (int j = 0; j < 4; ++j)
                    acc[i][j] = __builtin_amdgcn_mfma_f32_16x16x32_bf16(aF[i], bF[j], acc[i][j], 0, 0, 0);
        }
    }

    __syncthreads();
    {
        float* Crw = Cr + w * 4352;
        const int orow = fq * 4;
#pragma unroll
        for (int i = 0; i < 4; ++i)
#pragma unroll
            for (int j = 0; j < 4; ++j)
#pragma unroll
                for (int rr = 0; rr < 4; ++rr)
                    Crw[(i * 16 + orow + rr) * 68 + j * 16 + fr] = acc[i][j][rr];
    }
    __syncthreads();

    const int cc = (t & 15) * 4;
#pragma unroll
    for (int i = 0; i < 4; ++i) {
        const int row = (t >> 4) + i * 16;
        f32x4 s0 = *(const f32x4*)&Cr[0 * 4352 + row * 68 + cc];
        f32x4 s1 = *(const f32x4*)&Cr[1 * 4352 + row * 68 + cc];
        f32x4 s2 = *(const f32x4*)&Cr[2 * 4352 + row * 68 + cc];
        f32x4 s3 = *(const f32x4*)&Cr[3 * 4352 + row * 68 + cc];
        out[i] = (s0 + s1) + (s2 + s3);
    }
}

// ============================================================================
// proj: z in {0:Qm, 1:Qv, 2:K-fused(feat), 3:Vm, 4:Vv}; grid (16 n, 4 m, 5)
// Proj slots: 0 Qm, 1 Qv, 2 Vm, 3 Vv. K-fused emits Gbf/cvec directly.
// Weights read directly as f32 (no prep kernel, no WtB).
// ============================================================================
struct ProjArgs {
    const float* mu; const float* var;
    const float* W[6];      // q_mu, q_var, k_mu, k_var, v_mu, v_var (f32 [k][n])
    const float* bias[6];
    float* Proj;
    bf16_t* Gbf; float* cvec;
};

__global__ __launch_bounds__(256, 2) void proj_kernel(ProjArgs a) {
    __shared__ __align__(16) unsigned char smem[73728];
    const int z = blockIdx.z;
    const int nb = blockIdx.x * 64, mb = blockIdx.y * 64;
    const int t = threadIdx.x;
    const int cc = (t & 15) * 4;

    if (z != 2) {
        const int wi   = (z < 2) ? z : (z + 1);       // 0,1,4,5
        const int slot = (z < 2) ? z : (z - 1);       // 0,1,2,3
        const int sp   = (z == 1) || (z == 4);
        const void* A  = (z == 1 || z == 4) ? (const void*)a.var : (const void*)a.mu;
        f32x4 o[4];
        gemmT_core<true>(A, a.W[wi], mb, nb, smem, t, o);
        const f32x4 bv = *(const f32x4*)&a.bias[wi][nb + cc];
        float* dst = a.Proj + (size_t)slot * 262144;
#pragma unroll
        for (int i = 0; i < 4; ++i) {
            const int row = (t >> 4) + i * 16;
            f32x4 v = o[i] + bv;
            if (sp) {
                v[0] = softplus_f(v[0]); v[1] = softplus_f(v[1]);
                v[2] = softplus_f(v[2]); v[3] = softplus_f(v[3]);
            }
            *(f32x4*)&dst[(size_t)(mb + row) * 1024 + nb + cc] = v;
        }
    } else {
        // K projection (Km and Kv tiles) + feat epilogue; Km/Kv never hit HBM
        const int h = blockIdx.x;   // n-tile == head (64 cols per head)
        f32x4 okm[4], okv[4];
        gemmT_core<true>(a.mu,  a.W[2], mb, nb, smem, t, okm);
        gemmT_core<true>(a.var, a.W[3], mb, nb, smem, t, okv);
        const f32x4 bkm = *(const f32x4*)&a.bias[2][nb + cc];
        const f32x4 bkv = *(const f32x4*)&a.bias[3][nb + cc];
#pragma unroll
        for (int i = 0; i < 4; ++i) {
            const int row = (t >> 4) + i * 16;
            const int katt = mb + row;
            const f32x4 km  = okm[i] + bkm;
            const f32x4 kvr = okv[i] + bkv;
            bf16x4 o1, o2;
            float c = 0.f;
#pragma unroll
            for (int e = 0; e < 4; ++e) {
                const float kv = softplus_f(kvr[e]);
                const float r  = 0.5f * fast_rcp(kv);
                o1[e] = (bf16_t)r;
                o2[e] = (bf16_t)(-2.f * km[e] * r);
                c += km[e] * km[e] * r + 0.5f * __logf(kv);
            }
            bf16_t* grow = a.Gbf + ((size_t)(h * 256 + katt)) * 128;
            *(bf16x4*)&grow[cc]      = o1;
            *(bf16x4*)&grow[64 + cc] = o2;
            // reduce c across the 16 threads sharing this row
#pragma unroll
            for (int off = 8; off > 0; off >>= 1)
                c += __shfl_xor(c, off, 16);
            if ((t & 15) == 0)
                a.cvec[h * 256 + katt] = c;
        }
    }
}

// ============================================================================
// attention (verified attn_v7 structure, unchanged)
// ============================================================================
#define OFF_VM   0
#define OFF_VV   36864
#define OFF_FS   73728
#define OFF_SC   82176
#define OFF_PHI  98816
#define OFF_PLO  107264
#define OFF_P2H  115712
#define OFF_P2L  124160
#define ATTN_SMEM 132608

__global__ __launch_bounds__(512) void attn_v7(const float* __restrict__ Qm,
                                               const float* __restrict__ Qv,
                                               const bf16_t* __restrict__ Gbf,
                                               const float* __restrict__ cvec,
                                               const float* __restrict__ Vm,
                                               const float* __restrict__ Vv,
                                               bf16_t* __restrict__ Omu,
                                               bf16_t* __restrict__ Ovar) {
    __shared__ __align__(16) unsigned char smem[ATTN_SMEM];
    bf16_t* Vsm = (bf16_t*)(smem + OFF_VM);   // [256][72] bf16
    bf16_t* Vsv = (bf16_t*)(smem + OFF_VV);
    float*  Fs  = (float*)(smem + OFF_FS);    // [16][132] f32
    float*  Sc  = (float*)(smem + OFF_SC);    // [16][260] f32
    bf16_t* Phi = (bf16_t*)(smem + OFF_PHI);  // [16][264] bf16
    bf16_t* Plo = (bf16_t*)(smem + OFF_PLO);
    bf16_t* P2h = (bf16_t*)(smem + OFF_P2H);
    bf16_t* P2l = (bf16_t*)(smem + OFF_P2L);

    const int qt = blockIdx.x, h = blockIdx.y;
    const int t = threadIdx.x, w = t >> 6, lane = t & 63;
    const int fr = lane & 15, fq = lane >> 4;
    const int n0 = w * 32;

    const bf16_t* gB = Gbf + ((size_t)(h * 256 + n0 + fr)) * 128 + fq * 8;

    bf16x8 bcur[4];
#pragma unroll
    for (int ks = 0; ks < 4; ++ks) bcur[ks] = *(const bf16x8*)(gB + ks * 32);

    if (t < 256) {
        const int r = t >> 4, c = t & 15;
        f32x4 qm = *(const f32x4*)(Qm + (size_t)(qt * 16 + r) * 1024 + h * 64 + c * 4);
        f32x4 qv = *(const f32x4*)(Qv + (size_t)(qt * 16 + r) * 1024 + h * 64 + c * 4);
        *(f32x4*)&Fs[r * 132 + c * 4]      = qm * qm + qv;
        *(f32x4*)&Fs[r * 132 + 64 + c * 4] = qm;
    }
    __syncthreads();

    bf16x8 ahi[4], alo[4];
#pragma unroll
    for (int ks = 0; ks < 4; ++ks) {
        f32x4 f0 = *(const f32x4*)&Fs[fr * 132 + ks * 32 + fq * 8];
        f32x4 f1 = *(const f32x4*)&Fs[fr * 132 + ks * 32 + fq * 8 + 4];
#pragma unroll
        for (int e = 0; e < 4; ++e) {
            bf16_t hb = (bf16_t)f0[e];
            ahi[ks][e] = hb; alo[ks][e] = (bf16_t)(f0[e] - (float)hb);
            bf16_t hb2 = (bf16_t)f1[e];
            ahi[ks][e + 4] = hb2; alo[ks][e + 4] = (bf16_t)(f1[e] - (float)hb2);
        }
    }

    const int tm = t & 255;
    const int vk = tm >> 2, vpart = tm & 3;
    const float* Vsrc = (t >= 256) ? Vv : Vm;
    bf16_t*      Vdst = (t >= 256) ? Vsv : Vsm;

#pragma unroll
    for (int nt = 0; nt < 2; ++nt) {
        const int ra = vk + (2 * nt) * 64;
        const int rb = vk + (2 * nt + 1) * 64;
        const float* vsa = Vsrc + (size_t)ra * 1024 + h * 64 + vpart * 16;
        const float* vsb = Vsrc + (size_t)rb * 1024 + h * 64 + vpart * 16;
        f32x4 va0 = *(const f32x4*)(vsa),     va1 = *(const f32x4*)(vsa + 4);
        f32x4 va2 = *(const f32x4*)(vsa + 8), va3 = *(const f32x4*)(vsa + 12);
        f32x4 vb0 = *(const f32x4*)(vsb),     vb1 = *(const f32x4*)(vsb + 4);
        f32x4 vb2 = *(const f32x4*)(vsb + 8), vb3 = *(const f32x4*)(vsb + 12);

        bf16x8 bnxt[4];
        if (nt < 1) {
#pragma unroll
            for (int ks = 0; ks < 4; ++ks)
                bnxt[ks] = *(const bf16x8*)(gB + 2048 + ks * 32);
        }

        f32x4 acc = {0.f, 0.f, 0.f, 0.f};
#pragma unroll
        for (int ks = 0; ks < 4; ++ks) {
            acc = __builtin_amdgcn_mfma_f32_16x16x32_bf16(ahi[ks], bcur[ks], acc, 0, 0, 0);
            acc = __builtin_amdgcn_mfma_f32_16x16x32_bf16(alo[ks], bcur[ks], acc, 0, 0, 0);
        }

        {
            bf16_t* da = Vdst + ra * 72 + vpart * 16;
            bf16_t* db = Vdst + rb * 72 + vpart * 16;
            bf16x8 o0, o1;
            o0[0]=(bf16_t)va0[0]; o0[1]=(bf16_t)va0[1]; o0[2]=(bf16_t)va0[2]; o0[3]=(bf16_t)va0[3];
            o0[4]=(bf16_t)va1[0]; o0[5]=(bf16_t)va1[1]; o0[6]=(bf16_t)va1[2]; o0[7]=(bf16_t)va1[3];
            o1[0]=(bf16_t)va2[0]; o1[1]=(bf16_t)va2[1]; o1[2]=(bf16_t)va2[2]; o1[3]=(bf16_t)va2[3];
            o1[4]=(bf16_t)va3[0]; o1[5]=(bf16_t)va3[1]; o1[6]=(bf16_t)va3[2]; o1[7]=(bf16_t)va3[3];
            *(bf16x8*)(da)     = o0;
            *(bf16x8*)(da + 8) = o1;
            o0[0]=(bf16_t)vb0[0]; o0[1]=(bf16_t)vb0[1]; o0[2]=(bf16_t)vb0[2]; o0[3]=(bf16_t)vb0[3];
            o0[4]=(bf16_t)vb1[0]; o0[5]=(bf16_t)vb1[1]; o0[6]=(bf16_t)vb1[2]; o0[7]=(bf16_t)vb1[3];
            o1[0]=(bf16_t)vb2[0]; o1[1]=(bf16_t)vb2[1]; o1[2]=(bf16_t)vb2[2]; o1[3]=(bf16_t)vb2[3];
            o1[4]=(bf16_t)vb3[0]; o1[5]=(bf16_t)vb3[1]; o1[6]=(bf16_t)vb3[2]; o1[7]=(bf16_t)vb3[3];
            *(bf16x8*)(db)     = o0;
            *(bf16x8*)(db + 8) = o1;
        }

        const float cv = cvec[h * 256 + n0 + nt * 16 + fr];
        f32x4 lg = (acc + cv) * (-0.125f);
#pragma unroll
        for (int reg = 0; reg < 4; ++reg)
            Sc[(fq * 4 + reg) * 260 + n0 + nt * 16 + fr] = lg[reg];

#pragma unroll
        for (int ks = 0; ks < 4; ++ks) bcur[ks] = bnxt[ks];
    }
    __syncthreads();

    const int fw = w * 2;
    f32x4 sr[2];
#pragma unroll
    for (int r = 0; r < 2; ++r)
        sr[r] = *(const f32x4*)&Sc[(fw + r) * 260 + lane * 4];
#pragma unroll
    for (int r = 0; r < 2; ++r) {
        f32x4 s = sr[r];
        float mloc = fmaxf(fmaxf(s[0], s[1]), fmaxf(s[2], s[3]));
#pragma unroll
        for (int off = 32; off > 0; off >>= 1)
            mloc = fmaxf(mloc, __shfl_xor(mloc, off, 64));
        s[0] = __expf(s[0] - mloc); s[1] = __expf(s[1] - mloc);
        s[2] = __expf(s[2] - mloc); s[3] = __expf(s[3] - mloc);
        float sl = (s[0] + s[1]) + (s[2] + s[3]);
#pragma unroll
        for (int off = 32; off > 0; off >>= 1)
            sl += __shfl_xor(sl, off, 64);
        sr[r] = s * fast_rcp(sl);
    }

#pragma unroll
    for (int r = 0; r < 2; ++r) {
        bf16x4 phi, plo, p2hi, p2lo;
#pragma unroll
        for (int e = 0; e < 4; ++e) {
            const float p = sr[r][e];
            const bf16_t hb = (bf16_t)p;
            phi[e] = hb; plo[e] = (bf16_t)(p - (float)hb);
            const float p2 = p * p;
            const bf16_t h2 = (bf16_t)p2;
            p2hi[e] = h2; p2lo[e] = (bf16_t)(p2 - (float)h2);
        }
        const int row = fw + r;
        *(bf16x4*)&Phi[row * 264 + lane * 4] = phi;
        *(bf16x4*)&Plo[row * 264 + lane * 4] = plo;
        *(bf16x4*)&P2h[row * 264 + lane * 4] = p2hi;
        *(bf16x4*)&P2l[row * 264 + lane * 4] = p2lo;
    }
    __syncthreads();

    const int tile = w & 3;
    const int isvar = w >> 2;
    const bf16_t* Pa = isvar ? P2h : Phi;
    const bf16_t* Pb = isvar ? P2l : Plo;
    const bf16_t* Vs = isvar ? Vsv : Vsm;
    f32x4 accp = {0.f, 0.f, 0.f, 0.f};
#pragma unroll
    for (int k0 = 0; k0 < 256; k0 += 32) {
        const int ka = k0 + fq * 8;
        bf16x8 a1 = *(const bf16x8*)&Pa[fr * 264 + ka];
        bf16x8 a2 = *(const bf16x8*)&Pb[fr * 264 + ka];
        bf16x8 bfr;
#pragma unroll
        for (int j = 0; j < 8; ++j)
            bfr[j] = Vs[(ka + j) * 72 + tile * 16 + fr];
        accp = __builtin_amdgcn_mfma_f32_16x16x32_bf16(a1, bfr, accp, 0, 0, 0);
        accp = __builtin_amdgcn_mfma_f32_16x16x32_bf16(a2, bfr, accp, 0, 0, 0);
    }

    bf16_t* Out = isvar ? Ovar : Omu;
#pragma unroll
    for (int reg = 0; reg < 4; ++reg) {
        const int qg = qt * 16 + fq * 4 + reg;
        const size_t ob = (size_t)qg * 1024 + h * 64 + tile * 16 + fr;
        Out[ob] = (bf16_t)accp[reg];
    }
}

// ============================================================================
// output projection (bf16 A from attn, f32 W direct)
// ============================================================================
struct OutArgs {
    const bf16_t* A[2];
    const float*  W[2];
    const float*  bias[2];
    float*        dst[2];
    int           splus[2];
};

__global__ __launch_bounds__(256, 2) void out_gemm(OutArgs args) {
    const int z = blockIdx.z;
    const bf16_t* __restrict__ A    = args.A[z];
    const float*  __restrict__ W    = args.W[z];
    const float*  __restrict__ bias = args.bias[z];
    float*        __restrict__ dst  = args.dst[z];
    const int sp = args.splus[z];

    const int n_base = blockIdx.x * 64;
    const int m_base = blockIdx.y * 64;

    __shared__ __align__(16) unsigned char smem[73728];
    const int t = threadIdx.x;
    f32x4 o[4];
    gemmT_core<false>(A, W, m_base, n_base, smem, t, o);

    const int cc = (t & 15) * 4;
    const f32x4 bv = *(const f32x4*)&bias[n_base + cc];
#pragma unroll
    for (int i = 0; i < 4; ++i) {
        const int row = (t >> 4) + i * 16;
        f32x4 v = o[i] + bv;
        if (sp) {
            v[0] = softplus_f(v[0]); v[1] = softplus_f(v[1]);
            v[2] = softplus_f(v[2]); v[3] = softplus_f(v[3]);
        }
        *(f32x4*)&dst[(size_t)(m_base + row) * 1024 + n_base + cc] = v;
    }
}

// ---------------- launch ----------------
extern "C" void kernel_launch(void* const* d_in, const int* in_sizes, int n_in,
                              void* d_out, int out_size, void* d_ws, size_t ws_size,
                              hipStream_t stream) {
    const float* mu  = (const float*)d_in[0];
    const float* var = (const float*)d_in[1];
    uint8_t* ws = (uint8_t*)d_ws;

    float*  Proj = (float*)(ws);                               // 4 x 1 MB: Qm, Qv, Vm, Vv
    bf16_t* Obm  = (bf16_t*)(ws + (4u << 20));                 // 512 KB
    bf16_t* Obv  = (bf16_t*)(ws + (4u << 20) + (512u << 10));  // 512 KB
    bf16_t* Gbf  = (bf16_t*)(ws + (5u << 20));                 // 1 MB
    float*  cvec = (float*)(ws + (6u << 20));                  // 16 KB

    // 1) projections; K fused with feat; weights transposed on the fly
    ProjArgs pr;
    pr.mu = mu; pr.var = var;
    for (int i = 0; i < 6; ++i) {
        pr.W[i]    = (const float*)d_in[2 + 2 * i];
        pr.bias[i] = (const float*)d_in[3 + 2 * i];
    }
    pr.Proj = Proj; pr.Gbf = Gbf; pr.cvec = cvec;
    proj_kernel<<<dim3(16, 4, 5), 256, 0, stream>>>(pr);

    // 2) attention
    attn_v7<<<dim3(16, 16), 512, 0, stream>>>(Proj, Proj + 262144, Gbf, cvec,
                                              Proj + 2 * 262144, Proj + 3 * 262144,
                                              Obm, Obv);

    // 3) output projections
    OutArgs g3;
    g3.A[0] = Obm;  g3.W[0] = (const float*)d_in[14];
    g3.bias[0] = (const float*)d_in[15];
    g3.dst[0] = (float*)d_out;             g3.splus[0] = 0;
    g3.A[1] = Obv;  g3.W[1] = (const float*)d_in[16];
    g3.bias[1] = (const float*)d_in[17];
    g3.dst[1] = (float*)d_out + 262144;    g3.splus[1] = 1;
    out_gemm<<<dim3(16, 4, 2), 256, 0, stream>>>(g3);
}

// Round 4
// 144.510 us; speedup vs baseline: 2.7408x; 1.0278x over previous
//
#include <hip/hip_runtime.h>
#include <math.h>

typedef __bf16 bf16_t;
typedef bf16_t bf16x4 __attribute__((ext_vector_type(4)));
typedef bf16_t bf16x8 __attribute__((ext_vector_type(8)));
typedef float  f32x4  __attribute__((ext_vector_type(4)));

__device__ __forceinline__ float softplus_f(float x) {
    return (x > 20.f) ? x : log1pf(expf(x));
}

__device__ __forceinline__ float fast_rcp(float x) {
#if __has_builtin(__builtin_amdgcn_rcpf)
    return __builtin_amdgcn_rcpf(x);
#else
    return 1.0f / x;
#endif
}

// ============================================================================
// 4-wave GEMM core, on-the-fly B transpose (verified R3 structure), templated
// on MT = number of 16-row output groups (4 -> 64-row tile, 2 -> 32-row tile).
// B source: W f32 [k][n]. A: f32 (AF32) or bf16. Split-K 256/wave, 4 slices,
// register prefetch. Returns raw sums: out[i] = rows (t>>4)+i*16, cols (t&15)*4.
// ============================================================================
template<bool AF32, int MT>
__device__ __forceinline__ void gemmT_core(const void* Aptr, const float* __restrict__ Wf,
                                           const int m_base, const int n_base,
                                           unsigned char* smem, const int t, f32x4* out) {
    constexpr int NA = 2 * MT;   // A staging row-groups of 8
    __syncthreads();   // smem handoff from any previous use
    bf16_t* stage = (bf16_t*)smem;
    float*  Cr    = (float*)smem;
    const int lane = t & 63, w = t >> 6;
    bf16_t* As = stage + w * 9216;
    bf16_t* Bs = As + 4608;
    const int r8 = lane >> 3, kb = lane & 7;
    const int fr = lane & 15, fq = lane >> 4, fk = fq * 8;
    const int bc = fr;             // n-chunk (4 cols)
    const int br16 = fq * 16;      // k-row base (16 rows)

    const float*  Af = (const float*)Aptr  + (size_t)m_base * 1024 + w * 256 + kb * 8;
    const bf16_t* Ab = (const bf16_t*)Aptr + (size_t)m_base * 1024 + w * 256 + kb * 8;
    const float*  Bf = Wf + (size_t)(w * 256 + br16) * 1024 + n_base + bc * 4;

    f32x4 acc[MT][4] = {};
    bf16x8 pa[NA];
    f32x4 paf0[NA], paf1[NA];
    f32x4 pbf[16];

    // prologue: prefetch slice 0 (A and B) into registers
#pragma unroll
    for (int i = 0; i < NA; ++i) {
        if constexpr (AF32) {
            paf0[i] = *(const f32x4*)(Af + (size_t)(i * 8 + r8) * 1024);
            paf1[i] = *(const f32x4*)(Af + (size_t)(i * 8 + r8) * 1024 + 4);
        } else {
            pa[i] = *(const bf16x8*)(Ab + (size_t)(i * 8 + r8) * 1024);
        }
    }
#pragma unroll
    for (int i = 0; i < 16; ++i)
        pbf[i] = *(const f32x4*)(Bf + (size_t)i * 1024);

#pragma unroll
    for (int s = 0; s < 4; ++s) {
        // ---- write A slice to LDS ----
#pragma unroll
        for (int i = 0; i < NA; ++i) {
            bf16x8 av;
            if constexpr (AF32) {
#pragma unroll
                for (int e = 0; e < 4; ++e) {
                    av[e]     = (bf16_t)paf0[i][e];
                    av[e + 4] = (bf16_t)paf1[i][e];
                }
            } else {
                av = pa[i];
            }
            *(bf16x8*)&As[(i * 8 + r8) * 72 + kb * 8] = av;
        }
        // ---- write B slice transposed to LDS (Bs[n][72k]) ----
#pragma unroll
        for (int e = 0; e < 4; ++e) {
            bf16x8 lo, hi;
#pragma unroll
            for (int q = 0; q < 8; ++q) {
                lo[q] = (bf16_t)pbf[q][e];
                hi[q] = (bf16_t)pbf[q + 8][e];
            }
            *(bf16x8*)&Bs[(bc * 4 + e) * 72 + br16]     = lo;
            *(bf16x8*)&Bs[(bc * 4 + e) * 72 + br16 + 8] = hi;
        }
        if (s < 3) {   // issue next slice's loads; in flight during MFMA below
            const int off = (s + 1) * 64;
#pragma unroll
            for (int i = 0; i < NA; ++i) {
                if constexpr (AF32) {
                    paf0[i] = *(const f32x4*)(Af + (size_t)(i * 8 + r8) * 1024 + off);
                    paf1[i] = *(const f32x4*)(Af + (size_t)(i * 8 + r8) * 1024 + off + 4);
                } else {
                    pa[i] = *(const bf16x8*)(Ab + (size_t)(i * 8 + r8) * 1024 + off);
                }
            }
#pragma unroll
            for (int i = 0; i < 16; ++i)
                pbf[i] = *(const f32x4*)(Bf + (size_t)i * 1024 + (size_t)off * 1024);
        }
        // ---- MFMA on current slice ----
#pragma unroll
        for (int kh = 0; kh < 2; ++kh) {
            bf16x8 aF[MT], bF[4];
#pragma unroll
            for (int i = 0; i < MT; ++i)
                aF[i] = *(const bf16x8*)&As[(i * 16 + fr) * 72 + kh * 32 + fk];
#pragma unroll
            for (int j = 0; j < 4; ++j)
                bF[j] = *(const bf16x8*)&Bs[(j * 16 + fr) * 72 + kh * 32 + fk];
#pragma unroll
            for (int i = 0; i < MT; ++i)
#pragma unroll
                for (int j = 0; j < 4; ++j)
                    acc[i][j] = __builtin_amdgcn_mfma_f32_16x16x32_bf16(aF[i], bF[j], acc[i][j], 0, 0, 0);
        }
    }

    __syncthreads();
    {
        float* Crw = Cr + w * 4352;
        const int orow = fq * 4;
#pragma unroll
        for (int i = 0; i < MT; ++i)
#pragma unroll
            for (int j = 0; j < 4; ++j)
#pragma unroll
                for (int rr = 0; rr < 4; ++rr)
                    Crw[(i * 16 + orow + rr) * 68 + j * 16 + fr] = acc[i][j][rr];
    }
    __syncthreads();

    const int cc = (t & 15) * 4;
#pragma unroll
    for (int i = 0; i < MT; ++i) {
        const int row = (t >> 4) + i * 16;
        f32x4 s0 = *(const f32x4*)&Cr[0 * 4352 + row * 68 + cc];
        f32x4 s1 = *(const f32x4*)&Cr[1 * 4352 + row * 68 + cc];
        f32x4 s2 = *(const f32x4*)&Cr[2 * 4352 + row * 68 + cc];
        f32x4 s3 = *(const f32x4*)&Cr[3 * 4352 + row * 68 + cc];
        out[i] = (s0 + s1) + (s2 + s3);
    }
}

// ============================================================================
// proj: 1D grid, 384 blocks, XCD-co-scheduled (linear = xcd + 8*order).
//  - 256 type-A blocks: single 64x64 GEMM (z' 0:Qm 1:Qv 2:Vm 3:Vv),
//    group (z',nb) -> same XCD for the 4 m-tiles sharing a W column-slice.
//  - 128 type-K blocks: dual 32x64 GEMM (Km+Kv) + feat epilogue; group = head.
//    Balanced: every block has 128 serial MFMA.
// ============================================================================
struct ProjArgs {
    const float* mu; const float* var;
    const float* W[6];      // q_mu, q_var, k_mu, k_var, v_mu, v_var (f32 [k][n])
    const float* bias[6];
    float* Proj;            // slots: 0 Qm, 1 Qv, 2 Vm, 3 Vv
    bf16_t* Gbf; float* cvec;
};

__global__ __launch_bounds__(256, 2) void proj_kernel(ProjArgs a) {
    __shared__ __align__(16) unsigned char smem[73728];
    const int t = threadIdx.x;
    const int cc = (t & 15) * 4;
    const int L = blockIdx.x;
    const int x = L & 7;          // XCD slot
    const int o = L >> 3;         // order within XCD (0..47)

    if (o < 32) {
        // ---- type A: single 64x64 GEMM ----
        const int gA = (o >> 2) * 8 + x;        // 0..63 group (z',nb)
        const int m  = o & 3;
        const int zp = gA >> 4;                 // 0:Qm 1:Qv 2:Vm 3:Vv
        const int nb = (gA & 15) * 64;
        const int mb = m * 64;
        const int wi = (zp < 2) ? zp : (zp + 2);      // weight idx 0,1,4,5
        const int sp = (zp == 1) || (zp == 3);
        const void* A = sp ? (const void*)a.var : (const void*)a.mu;
        f32x4 ov[4];
        gemmT_core<true, 4>(A, a.W[wi], mb, nb, smem, t, ov);
        const f32x4 bv = *(const f32x4*)&a.bias[wi][nb + cc];
        float* dst = a.Proj + (size_t)zp * 262144;
#pragma unroll
        for (int i = 0; i < 4; ++i) {
            const int row = (t >> 4) + i * 16;
            f32x4 v = ov[i] + bv;
            if (sp) {
                v[0] = softplus_f(v[0]); v[1] = softplus_f(v[1]);
                v[2] = softplus_f(v[2]); v[3] = softplus_f(v[3]);
            }
            *(f32x4*)&dst[(size_t)(mb + row) * 1024 + nb + cc] = v;
        }
    } else {
        // ---- type K: dual 32x64 GEMM (Km, Kv) + feat epilogue ----
        const int op = o - 32;                  // 0..15
        const int h  = (op >> 3) * 8 + x;       // head 0..15
        const int m  = op & 7;                  // m-half 0..7
        const int mb = m * 32;
        const int nb = h * 64;
        f32x4 okm[2], okv[2];
        gemmT_core<true, 2>(a.mu,  a.W[2], mb, nb, smem, t, okm);
        gemmT_core<true, 2>(a.var, a.W[3], mb, nb, smem, t, okv);
        const f32x4 bkm = *(const f32x4*)&a.bias[2][nb + cc];
        const f32x4 bkv = *(const f32x4*)&a.bias[3][nb + cc];
#pragma unroll
        for (int i = 0; i < 2; ++i) {
            const int row = (t >> 4) + i * 16;
            const int katt = mb + row;
            const f32x4 km  = okm[i] + bkm;
            const f32x4 kvr = okv[i] + bkv;
            bf16x4 o1, o2;
            float c = 0.f;
#pragma unroll
            for (int e = 0; e < 4; ++e) {
                const float kv = softplus_f(kvr[e]);
                const float r  = 0.5f * fast_rcp(kv);
                o1[e] = (bf16_t)r;
                o2[e] = (bf16_t)(-2.f * km[e] * r);
                c += km[e] * km[e] * r + 0.5f * __logf(kv);
            }
            bf16_t* grow = a.Gbf + ((size_t)(h * 256 + katt)) * 128;
            *(bf16x4*)&grow[cc]      = o1;
            *(bf16x4*)&grow[64 + cc] = o2;
#pragma unroll
            for (int off = 8; off > 0; off >>= 1)
                c += __shfl_xor(c, off, 16);
            if ((t & 15) == 0)
                a.cvec[h * 256 + katt] = c;
        }
    }
}

// ============================================================================
// attention (verified attn_v7 body); 1D grid, head-major XCD co-scheduling
// ============================================================================
#define OFF_VM   0
#define OFF_VV   36864
#define OFF_FS   73728
#define OFF_SC   82176
#define OFF_PHI  98816
#define OFF_PLO  107264
#define OFF_P2H  115712
#define OFF_P2L  124160
#define ATTN_SMEM 132608

__global__ __launch_bounds__(512) void attn_v7(const float* __restrict__ Qm,
                                               const float* __restrict__ Qv,
                                               const bf16_t* __restrict__ Gbf,
                                               const float* __restrict__ cvec,
                                               const float* __restrict__ Vm,
                                               const float* __restrict__ Vv,
                                               bf16_t* __restrict__ Omu,
                                               bf16_t* __restrict__ Ovar) {
    __shared__ __align__(16) unsigned char smem[ATTN_SMEM];
    bf16_t* Vsm = (bf16_t*)(smem + OFF_VM);   // [256][72] bf16
    bf16_t* Vsv = (bf16_t*)(smem + OFF_VV);
    float*  Fs  = (float*)(smem + OFF_FS);    // [16][132] f32
    float*  Sc  = (float*)(smem + OFF_SC);    // [16][260] f32
    bf16_t* Phi = (bf16_t*)(smem + OFF_PHI);  // [16][264] bf16
    bf16_t* Plo = (bf16_t*)(smem + OFF_PLO);
    bf16_t* P2h = (bf16_t*)(smem + OFF_P2H);
    bf16_t* P2l = (bf16_t*)(smem + OFF_P2L);

    // 1D decode: blocks sharing a head land on one XCD (G/V L2 locality)
    const int L = blockIdx.x;
    const int h  = ((L >> 7) << 3) + (L & 7);   // (order>>4)*8 + xcd
    const int qt = (L >> 3) & 15;

    const int t = threadIdx.x, w = t >> 6, lane = t & 63;
    const int fr = lane & 15, fq = lane >> 4;
    const int n0 = w * 32;

    const bf16_t* gB = Gbf + ((size_t)(h * 256 + n0 + fr)) * 128 + fq * 8;

    bf16x8 bcur[4];
#pragma unroll
    for (int ks = 0; ks < 4; ++ks) bcur[ks] = *(const bf16x8*)(gB + ks * 32);

    if (t < 256) {
        const int r = t >> 4, c = t & 15;
        f32x4 qm = *(const f32x4*)(Qm + (size_t)(qt * 16 + r) * 1024 + h * 64 + c * 4);
        f32x4 qv = *(const f32x4*)(Qv + (size_t)(qt * 16 + r) * 1024 + h * 64 + c * 4);
        *(f32x4*)&Fs[r * 132 + c * 4]      = qm * qm + qv;
        *(f32x4*)&Fs[r * 132 + 64 + c * 4] = qm;
    }
    __syncthreads();

    bf16x8 ahi[4], alo[4];
#pragma unroll
    for (int ks = 0; ks < 4; ++ks) {
        f32x4 f0 = *(const f32x4*)&Fs[fr * 132 + ks * 32 + fq * 8];
        f32x4 f1 = *(const f32x4*)&Fs[fr * 132 + ks * 32 + fq * 8 + 4];
#pragma unroll
        for (int e = 0; e < 4; ++e) {
            bf16_t hb = (bf16_t)f0[e];
            ahi[ks][e] = hb; alo[ks][e] = (bf16_t)(f0[e] - (float)hb);
            bf16_t hb2 = (bf16_t)f1[e];
            ahi[ks][e + 4] = hb2; alo[ks][e + 4] = (bf16_t)(f1[e] - (float)hb2);
        }
    }

    const int tm = t & 255;
    const int vk = tm >> 2, vpart = tm & 3;
    const float* Vsrc = (t >= 256) ? Vv : Vm;
    bf16_t*      Vdst = (t >= 256) ? Vsv : Vsm;

#pragma unroll
    for (int nt = 0; nt < 2; ++nt) {
        const int ra = vk + (2 * nt) * 64;
        const int rb = vk + (2 * nt + 1) * 64;
        const float* vsa = Vsrc + (size_t)ra * 1024 + h * 64 + vpart * 16;
        const float* vsb = Vsrc + (size_t)rb * 1024 + h * 64 + vpart * 16;
        f32x4 va0 = *(const f32x4*)(vsa),     va1 = *(const f32x4*)(vsa + 4);
        f32x4 va2 = *(const f32x4*)(vsa + 8), va3 = *(const f32x4*)(vsa + 12);
        f32x4 vb0 = *(const f32x4*)(vsb),     vb1 = *(const f32x4*)(vsb + 4);
        f32x4 vb2 = *(const f32x4*)(vsb + 8), vb3 = *(const f32x4*)(vsb + 12);

        bf16x8 bnxt[4];
        if (nt < 1) {
#pragma unroll
            for (int ks = 0; ks < 4; ++ks)
                bnxt[ks] = *(const bf16x8*)(gB + 2048 + ks * 32);
        }

        f32x4 acc = {0.f, 0.f, 0.f, 0.f};
#pragma unroll
        for (int ks = 0; ks < 4; ++ks) {
            acc = __builtin_amdgcn_mfma_f32_16x16x32_bf16(ahi[ks], bcur[ks], acc, 0, 0, 0);
            acc = __builtin_amdgcn_mfma_f32_16x16x32_bf16(alo[ks], bcur[ks], acc, 0, 0, 0);
        }

        {
            bf16_t* da = Vdst + ra * 72 + vpart * 16;
            bf16_t* db = Vdst + rb * 72 + vpart * 16;
            bf16x8 o0, o1;
            o0[0]=(bf16_t)va0[0]; o0[1]=(bf16_t)va0[1]; o0[2]=(bf16_t)va0[2]; o0[3]=(bf16_t)va0[3];
            o0[4]=(bf16_t)va1[0]; o0[5]=(bf16_t)va1[1]; o0[6]=(bf16_t)va1[2]; o0[7]=(bf16_t)va1[3];
            o1[0]=(bf16_t)va2[0]; o1[1]=(bf16_t)va2[1]; o1[2]=(bf16_t)va2[2]; o1[3]=(bf16_t)va2[3];
            o1[4]=(bf16_t)va3[0]; o1[5]=(bf16_t)va3[1]; o1[6]=(bf16_t)va3[2]; o1[7]=(bf16_t)va3[3];
            *(bf16x8*)(da)     = o0;
            *(bf16x8*)(da + 8) = o1;
            o0[0]=(bf16_t)vb0[0]; o0[1]=(bf16_t)vb0[1]; o0[2]=(bf16_t)vb0[2]; o0[3]=(bf16_t)vb0[3];
            o0[4]=(bf16_t)vb1[0]; o0[5]=(bf16_t)vb1[1]; o0[6]=(bf16_t)vb1[2]; o0[7]=(bf16_t)vb1[3];
            o1[0]=(bf16_t)vb2[0]; o1[1]=(bf16_t)vb2[1]; o1[2]=(bf16_t)vb2[2]; o1[3]=(bf16_t)vb2[3];
            o1[4]=(bf16_t)vb3[0]; o1[5]=(bf16_t)vb3[1]; o1[6]=(bf16_t)vb3[2]; o1[7]=(bf16_t)vb3[3];
            *(bf16x8*)(db)     = o0;
            *(bf16x8*)(db + 8) = o1;
        }

        const float cv = cvec[h * 256 + n0 + nt * 16 + fr];
        f32x4 lg = (acc + cv) * (-0.125f);
#pragma unroll
        for (int reg = 0; reg < 4; ++reg)
            Sc[(fq * 4 + reg) * 260 + n0 + nt * 16 + fr] = lg[reg];

#pragma unroll
        for (int ks = 0; ks < 4; ++ks) bcur[ks] = bnxt[ks];
    }
    __syncthreads();

    const int fw = w * 2;
    f32x4 sr[2];
#pragma unroll
    for (int r = 0; r < 2; ++r)
        sr[r] = *(const f32x4*)&Sc[(fw + r) * 260 + lane * 4];
#pragma unroll
    for (int r = 0; r < 2; ++r) {
        f32x4 s = sr[r];
        float mloc = fmaxf(fmaxf(s[0], s[1]), fmaxf(s[2], s[3]));
#pragma unroll
        for (int off = 32; off > 0; off >>= 1)
            mloc = fmaxf(mloc, __shfl_xor(mloc, off, 64));
        s[0] = __expf(s[0] - mloc); s[1] = __expf(s[1] - mloc);
        s[2] = __expf(s[2] - mloc); s[3] = __expf(s[3] - mloc);
        float sl = (s[0] + s[1]) + (s[2] + s[3]);
#pragma unroll
        for (int off = 32; off > 0; off >>= 1)
            sl += __shfl_xor(sl, off, 64);
        sr[r] = s * fast_rcp(sl);
    }

#pragma unroll
    for (int r = 0; r < 2; ++r) {
        bf16x4 phi, plo, p2hi, p2lo;
#pragma unroll
        for (int e = 0; e < 4; ++e) {
            const float p = sr[r][e];
            const bf16_t hb = (bf16_t)p;
            phi[e] = hb; plo[e] = (bf16_t)(p - (float)hb);
            const float p2 = p * p;
            const bf16_t h2 = (bf16_t)p2;
            p2hi[e] = h2; p2lo[e] = (bf16_t)(p2 - (float)h2);
        }
        const int row = fw + r;
        *(bf16x4*)&Phi[row * 264 + lane * 4] = phi;
        *(bf16x4*)&Plo[row * 264 + lane * 4] = plo;
        *(bf16x4*)&P2h[row * 264 + lane * 4] = p2hi;
        *(bf16x4*)&P2l[row * 264 + lane * 4] = p2lo;
    }
    __syncthreads();

    const int tile = w & 3;
    const int isvar = w >> 2;
    const bf16_t* Pa = isvar ? P2h : Phi;
    const bf16_t* Pb = isvar ? P2l : Plo;
    const bf16_t* Vs = isvar ? Vsv : Vsm;
    f32x4 accp = {0.f, 0.f, 0.f, 0.f};
#pragma unroll
    for (int k0 = 0; k0 < 256; k0 += 32) {
        const int ka = k0 + fq * 8;
        bf16x8 a1 = *(const bf16x8*)&Pa[fr * 264 + ka];
        bf16x8 a2 = *(const bf16x8*)&Pb[fr * 264 + ka];
        bf16x8 bfr;
#pragma unroll
        for (int j = 0; j < 8; ++j)
            bfr[j] = Vs[(ka + j) * 72 + tile * 16 + fr];
        accp = __builtin_amdgcn_mfma_f32_16x16x32_bf16(a1, bfr, accp, 0, 0, 0);
        accp = __builtin_amdgcn_mfma_f32_16x16x32_bf16(a2, bfr, accp, 0, 0, 0);
    }

    bf16_t* Out = isvar ? Ovar : Omu;
#pragma unroll
    for (int reg = 0; reg < 4; ++reg) {
        const int qg = qt * 16 + fq * 4 + reg;
        const size_t ob = (size_t)qg * 1024 + h * 64 + tile * 16 + fr;
        Out[ob] = (bf16_t)accp[reg];
    }
}

// ============================================================================
// output projection: 1D grid, 128 blocks, XCD co-scheduling on (z,nb)
// ============================================================================
struct OutArgs {
    const bf16_t* A[2];
    const float*  W[2];
    const float*  bias[2];
    float*        dst[2];
    int           splus[2];
};

__global__ __launch_bounds__(256, 2) void out_gemm(OutArgs args) {
    __shared__ __align__(16) unsigned char smem[73728];
    const int t = threadIdx.x;
    const int L = blockIdx.x;
    const int x = L & 7, o = L >> 3;            // o 0..15
    const int g = (o >> 2) * 8 + x;             // group (z,nb) 0..31
    const int m = o & 3;
    const int z = g >> 4;
    const int n_base = (g & 15) * 64;
    const int m_base = m * 64;

    const bf16_t* __restrict__ A    = args.A[z];
    const float*  __restrict__ W    = args.W[z];
    const float*  __restrict__ bias = args.bias[z];
    float*        __restrict__ dst  = args.dst[z];
    const int sp = args.splus[z];

    f32x4 ov[4];
    gemmT_core<false, 4>(A, W, m_base, n_base, smem, t, ov);

    const int cc = (t & 15) * 4;
    const f32x4 bv = *(const f32x4*)&bias[n_base + cc];
#pragma unroll
    for (int i = 0; i < 4; ++i) {
        const int row = (t >> 4) + i * 16;
        f32x4 v = ov[i] + bv;
        if (sp) {
            v[0] = softplus_f(v[0]); v[1] = softplus_f(v[1]);
            v[2] = softplus_f(v[2]); v[3] = softplus_f(v[3]);
        }
        *(f32x4*)&dst[(size_t)(m_base + row) * 1024 + n_base + cc] = v;
    }
}

// ---------------- launch ----------------
extern "C" void kernel_launch(void* const* d_in, const int* in_sizes, int n_in,
                              void* d_out, int out_size, void* d_ws, size_t ws_size,
                              hipStream_t stream) {
    const float* mu  = (const float*)d_in[0];
    const float* var = (const float*)d_in[1];
    uint8_t* ws = (uint8_t*)d_ws;

    float*  Proj = (float*)(ws);                               // 4 x 1 MB: Qm, Qv, Vm, Vv
    bf16_t* Obm  = (bf16_t*)(ws + (4u << 20));                 // 512 KB
    bf16_t* Obv  = (bf16_t*)(ws + (4u << 20) + (512u << 10));  // 512 KB
    bf16_t* Gbf  = (bf16_t*)(ws + (5u << 20));                 // 1 MB
    float*  cvec = (float*)(ws + (6u << 20));                  // 16 KB

    // 1) projections; K fused with feat; balanced blocks; XCD co-scheduling
    ProjArgs pr;
    pr.mu = mu; pr.var = var;
    for (int i = 0; i < 6; ++i) {
        pr.W[i]    = (const float*)d_in[2 + 2 * i];
        pr.bias[i] = (const float*)d_in[3 + 2 * i];
    }
    pr.Proj = Proj; pr.Gbf = Gbf; pr.cvec = cvec;
    proj_kernel<<<dim3(384), 256, 0, stream>>>(pr);

    // 2) attention
    attn_v7<<<dim3(256), 512, 0, stream>>>(Proj, Proj + 262144, Gbf, cvec,
                                           Proj + 2 * 262144, Proj + 3 * 262144,
                                           Obm, Obv);

    // 3) output projections
    OutArgs g3;
    g3.A[0] = Obm;  g3.W[0] = (const float*)d_in[14];
    g3.bias[0] = (const float*)d_in[15];
    g3.dst[0] = (float*)d_out;             g3.splus[0] = 0;
    g3.A[1] = Obv;  g3.W[1] = (const float*)d_in[16];
    g3.bias[1] = (const float*)d_in[17];
    g3.dst[1] = (float*)d_out + 262144;    g3.splus[1] = 1;
    out_gemm<<<dim3(128), 256, 0, stream>>>(g3);
}

// Round 5
// 142.709 us; speedup vs baseline: 2.7754x; 1.0126x over previous
//
#include <hip/hip_runtime.h>
#include <math.h>

typedef __bf16 bf16_t;
typedef bf16_t bf16x4 __attribute__((ext_vector_type(4)));
typedef bf16_t bf16x8 __attribute__((ext_vector_type(8)));
typedef float  f32x4  __attribute__((ext_vector_type(4)));

__device__ __forceinline__ float softplus_f(float x) {
    return (x > 20.f) ? x : log1pf(expf(x));
}

__device__ __forceinline__ float fast_rcp(float x) {
#if __has_builtin(__builtin_amdgcn_rcpf)
    return __builtin_amdgcn_rcpf(x);
#else
    return 1.0f / x;
#endif
}

// ============================================================================
// 4-wave GEMM core, on-the-fly B transpose (verified R3/R4 structure).
// MT = 16-row output groups (4 -> 64 rows). B: W f32 [k][n]. A: f32 or bf16.
// Split-K 256/wave, 4 slices, register prefetch. out[i] raw sums.
// ============================================================================
template<bool AF32, int MT>
__device__ __forceinline__ void gemmT_core(const void* Aptr, const float* __restrict__ Wf,
                                           const int m_base, const int n_base,
                                           unsigned char* smem, const int t, f32x4* out) {
    constexpr int NA = 2 * MT;
    __syncthreads();
    bf16_t* stage = (bf16_t*)smem;
    float*  Cr    = (float*)smem;
    const int lane = t & 63, w = t >> 6;
    bf16_t* As = stage + w * 9216;
    bf16_t* Bs = As + 4608;
    const int r8 = lane >> 3, kb = lane & 7;
    const int fr = lane & 15, fq = lane >> 4, fk = fq * 8;
    const int bc = fr;
    const int br16 = fq * 16;

    const float*  Af = (const float*)Aptr  + (size_t)m_base * 1024 + w * 256 + kb * 8;
    const bf16_t* Ab = (const bf16_t*)Aptr + (size_t)m_base * 1024 + w * 256 + kb * 8;
    const float*  Bf = Wf + (size_t)(w * 256 + br16) * 1024 + n_base + bc * 4;

    f32x4 acc[MT][4] = {};
    bf16x8 pa[NA];
    f32x4 paf0[NA], paf1[NA];
    f32x4 pbf[16];

#pragma unroll
    for (int i = 0; i < NA; ++i) {
        if constexpr (AF32) {
            paf0[i] = *(const f32x4*)(Af + (size_t)(i * 8 + r8) * 1024);
            paf1[i] = *(const f32x4*)(Af + (size_t)(i * 8 + r8) * 1024 + 4);
        } else {
            pa[i] = *(const bf16x8*)(Ab + (size_t)(i * 8 + r8) * 1024);
        }
    }
#pragma unroll
    for (int i = 0; i < 16; ++i)
        pbf[i] = *(const f32x4*)(Bf + (size_t)i * 1024);

#pragma unroll
    for (int s = 0; s < 4; ++s) {
#pragma unroll
        for (int i = 0; i < NA; ++i) {
            bf16x8 av;
            if constexpr (AF32) {
#pragma unroll
                for (int e = 0; e < 4; ++e) {
                    av[e]     = (bf16_t)paf0[i][e];
                    av[e + 4] = (bf16_t)paf1[i][e];
                }
            } else {
                av = pa[i];
            }
            *(bf16x8*)&As[(i * 8 + r8) * 72 + kb * 8] = av;
        }
#pragma unroll
        for (int e = 0; e < 4; ++e) {
            bf16x8 lo, hi;
#pragma unroll
            for (int q = 0; q < 8; ++q) {
                lo[q] = (bf16_t)pbf[q][e];
                hi[q] = (bf16_t)pbf[q + 8][e];
            }
            *(bf16x8*)&Bs[(bc * 4 + e) * 72 + br16]     = lo;
            *(bf16x8*)&Bs[(bc * 4 + e) * 72 + br16 + 8] = hi;
        }
        if (s < 3) {
            const int off = (s + 1) * 64;
#pragma unroll
            for (int i = 0; i < NA; ++i) {
                if constexpr (AF32) {
                    paf0[i] = *(const f32x4*)(Af + (size_t)(i * 8 + r8) * 1024 + off);
                    paf1[i] = *(const f32x4*)(Af + (size_t)(i * 8 + r8) * 1024 + off + 4);
                } else {
                    pa[i] = *(const bf16x8*)(Ab + (size_t)(i * 8 + r8) * 1024 + off);
                }
            }
#pragma unroll
            for (int i = 0; i < 16; ++i)
                pbf[i] = *(const f32x4*)(Bf + (size_t)i * 1024 + (size_t)off * 1024);
        }
#pragma unroll
        for (int kh = 0; kh < 2; ++kh) {
            bf16x8 aF[MT], bF[4];
#pragma unroll
            for (int i = 0; i < MT; ++i)
                aF[i] = *(const bf16x8*)&As[(i * 16 + fr) * 72 + kh * 32 + fk];
#pragma unroll
            for (int j = 0; j < 4; ++j)
                bF[j] = *(const bf16x8*)&Bs[(j * 16 + fr) * 72 + kh * 32 + fk];
#pragma unroll
            for (int i = 0; i < MT; ++i)
#pragma unroll
                for (int j = 0; j < 4; ++j)
                    acc[i][j] = __builtin_amdgcn_mfma_f32_16x16x32_bf16(aF[i], bF[j], acc[i][j], 0, 0, 0);
        }
    }

    __syncthreads();
    {
        float* Crw = Cr + w * 4352;
        const int orow = fq * 4;
#pragma unroll
        for (int i = 0; i < MT; ++i)
#pragma unroll
            for (int j = 0; j < 4; ++j)
#pragma unroll
                for (int rr = 0; rr < 4; ++rr)
                    Crw[(i * 16 + orow + rr) * 68 + j * 16 + fr] = acc[i][j][rr];
    }
    __syncthreads();

    const int cc = (t & 15) * 4;
#pragma unroll
    for (int i = 0; i < MT; ++i) {
        const int row = (t >> 4) + i * 16;
        f32x4 s0 = *(const f32x4*)&Cr[0 * 4352 + row * 68 + cc];
        f32x4 s1 = *(const f32x4*)&Cr[1 * 4352 + row * 68 + cc];
        f32x4 s2 = *(const f32x4*)&Cr[2 * 4352 + row * 68 + cc];
        f32x4 s3 = *(const f32x4*)&Cr[3 * 4352 + row * 68 + cc];
        out[i] = (s0 + s1) + (s2 + s3);
    }
}

// ============================================================================
// Dual-GEMM K core: ONE 8-slice pipeline. Waves 0-1 compute Km (split-K 512
// each: wave0 K[0,512), wave1 K[512,1024)); waves 2-3 compute Kv likewise.
// 32-row tile (MT=2). Epilogue: okm = Cr[0]+Cr[1], okv = Cr[2]+Cr[3].
// Same LDS layouts / MFMA fragments as gemmT_core (verified).
// ============================================================================
__device__ __forceinline__ void gemmK_dual(const float* __restrict__ mu,
                                           const float* __restrict__ var,
                                           const float* __restrict__ Wkm,
                                           const float* __restrict__ Wkv,
                                           const int m_base, const int n_base,
                                           unsigned char* smem, const int t,
                                           f32x4 okm[2], f32x4 okv[2]) {
    __syncthreads();
    bf16_t* stage = (bf16_t*)smem;
    float*  Cr    = (float*)smem;
    const int lane = t & 63, w = t >> 6;
    bf16_t* As = stage + w * 9216;
    bf16_t* Bs = As + 4608;
    const int r8 = lane >> 3, kb = lane & 7;
    const int fr = lane & 15, fq = lane >> 4, fk = fq * 8;
    const int bc = fr;
    const int br16 = fq * 16;

    const float* Asrc = (w < 2) ? mu : var;
    const float* Wsrc = (w < 2) ? Wkm : Wkv;
    const int kbase = (w & 1) * 512;

    const float* Af = Asrc + (size_t)m_base * 1024 + kbase + kb * 8;
    const float* Bf = Wsrc + (size_t)(kbase + br16) * 1024 + n_base + bc * 4;

    f32x4 acc[2][4] = {};
    f32x4 paf0[4], paf1[4];
    f32x4 pbf[16];

#pragma unroll
    for (int i = 0; i < 4; ++i) {
        paf0[i] = *(const f32x4*)(Af + (size_t)(i * 8 + r8) * 1024);
        paf1[i] = *(const f32x4*)(Af + (size_t)(i * 8 + r8) * 1024 + 4);
    }
#pragma unroll
    for (int i = 0; i < 16; ++i)
        pbf[i] = *(const f32x4*)(Bf + (size_t)i * 1024);

#pragma unroll
    for (int s = 0; s < 8; ++s) {
#pragma unroll
        for (int i = 0; i < 4; ++i) {
            bf16x8 av;
#pragma unroll
            for (int e = 0; e < 4; ++e) {
                av[e]     = (bf16_t)paf0[i][e];
                av[e + 4] = (bf16_t)paf1[i][e];
            }
            *(bf16x8*)&As[(i * 8 + r8) * 72 + kb * 8] = av;
        }
#pragma unroll
        for (int e = 0; e < 4; ++e) {
            bf16x8 lo, hi;
#pragma unroll
            for (int q = 0; q < 8; ++q) {
                lo[q] = (bf16_t)pbf[q][e];
                hi[q] = (bf16_t)pbf[q + 8][e];
            }
            *(bf16x8*)&Bs[(bc * 4 + e) * 72 + br16]     = lo;
            *(bf16x8*)&Bs[(bc * 4 + e) * 72 + br16 + 8] = hi;
        }
        if (s < 7) {
            const int off = (s + 1) * 64;
#pragma unroll
            for (int i = 0; i < 4; ++i) {
                paf0[i] = *(const f32x4*)(Af + (size_t)(i * 8 + r8) * 1024 + off);
                paf1[i] = *(const f32x4*)(Af + (size_t)(i * 8 + r8) * 1024 + off + 4);
            }
#pragma unroll
            for (int i = 0; i < 16; ++i)
                pbf[i] = *(const f32x4*)(Bf + (size_t)i * 1024 + (size_t)off * 1024);
        }
#pragma unroll
        for (int kh = 0; kh < 2; ++kh) {
            bf16x8 aF[2], bF[4];
#pragma unroll
            for (int i = 0; i < 2; ++i)
                aF[i] = *(const bf16x8*)&As[(i * 16 + fr) * 72 + kh * 32 + fk];
#pragma unroll
            for (int j = 0; j < 4; ++j)
                bF[j] = *(const bf16x8*)&Bs[(j * 16 + fr) * 72 + kh * 32 + fk];
#pragma unroll
            for (int i = 0; i < 2; ++i)
#pragma unroll
                for (int j = 0; j < 4; ++j)
                    acc[i][j] = __builtin_amdgcn_mfma_f32_16x16x32_bf16(aF[i], bF[j], acc[i][j], 0, 0, 0);
        }
    }

    __syncthreads();
    {
        float* Crw = Cr + w * 4352;
        const int orow = fq * 4;
#pragma unroll
        for (int i = 0; i < 2; ++i)
#pragma unroll
            for (int j = 0; j < 4; ++j)
#pragma unroll
                for (int rr = 0; rr < 4; ++rr)
                    Crw[(i * 16 + orow + rr) * 68 + j * 16 + fr] = acc[i][j][rr];
    }
    __syncthreads();

    const int cc = (t & 15) * 4;
#pragma unroll
    for (int i = 0; i < 2; ++i) {
        const int row = (t >> 4) + i * 16;
        okm[i] = *(const f32x4*)&Cr[0 * 4352 + row * 68 + cc]
               + *(const f32x4*)&Cr[1 * 4352 + row * 68 + cc];
        okv[i] = *(const f32x4*)&Cr[2 * 4352 + row * 68 + cc]
               + *(const f32x4*)&Cr[3 * 4352 + row * 68 + cc];
    }
}

// ============================================================================
// proj: 1D grid, 384 blocks, XCD-co-scheduled (linear = xcd + 8*order).
//  - 256 type-A blocks: 64x64 GEMM. zp 0:Qm 1:Qv -> f32 Proj; 2:Vm 3:Vv -> bf16 V.
//  - 128 type-K blocks: dual 32x64 GEMM (Km+Kv, single pipeline) + feat epilogue.
// ============================================================================
struct ProjArgs {
    const float* mu; const float* var;
    const float* W[6];      // q_mu, q_var, k_mu, k_var, v_mu, v_var (f32 [k][n])
    const float* bias[6];
    float* Proj;            // slots: 0 Qm, 1 Qv (f32)
    bf16_t* Vbm; bf16_t* Vbv;   // [16 head][256 katt][64 d] bf16
    bf16_t* Gbf; float* cvec;
};

__global__ __launch_bounds__(256, 2) void proj_kernel(ProjArgs a) {
    __shared__ __align__(16) unsigned char smem[73728];
    const int t = threadIdx.x;
    const int cc = (t & 15) * 4;
    const int L = blockIdx.x;
    const int x = L & 7;
    const int o = L >> 3;

    if (o < 32) {
        // ---- type A: single 64x64 GEMM ----
        const int gA = (o >> 2) * 8 + x;
        const int m  = o & 3;
        const int zp = gA >> 4;                 // 0:Qm 1:Qv 2:Vm 3:Vv
        const int nb = (gA & 15) * 64;
        const int mb = m * 64;
        const int wi = (zp < 2) ? zp : (zp + 2);
        const int sp = (zp == 1) || (zp == 3);
        const void* A = sp ? (const void*)a.var : (const void*)a.mu;
        f32x4 ov[4];
        gemmT_core<true, 4>(A, a.W[wi], mb, nb, smem, t, ov);
        const f32x4 bv = *(const f32x4*)&a.bias[wi][nb + cc];
        if (zp < 2) {
            float* dst = a.Proj + (size_t)zp * 262144;
#pragma unroll
            for (int i = 0; i < 4; ++i) {
                const int row = (t >> 4) + i * 16;
                f32x4 v = ov[i] + bv;
                if (sp) {
                    v[0] = softplus_f(v[0]); v[1] = softplus_f(v[1]);
                    v[2] = softplus_f(v[2]); v[3] = softplus_f(v[3]);
                }
                *(f32x4*)&dst[(size_t)(mb + row) * 1024 + nb + cc] = v;
            }
        } else {
            // V outputs stored bf16 [head][katt][64]
            bf16_t* dst = ((zp == 2) ? a.Vbm : a.Vbv) + (size_t)(nb >> 6) * 16384;
#pragma unroll
            for (int i = 0; i < 4; ++i) {
                const int row = (t >> 4) + i * 16;
                f32x4 v = ov[i] + bv;
                if (sp) {
                    v[0] = softplus_f(v[0]); v[1] = softplus_f(v[1]);
                    v[2] = softplus_f(v[2]); v[3] = softplus_f(v[3]);
                }
                bf16x4 o4;
                o4[0] = (bf16_t)v[0]; o4[1] = (bf16_t)v[1];
                o4[2] = (bf16_t)v[2]; o4[3] = (bf16_t)v[3];
                *(bf16x4*)&dst[(size_t)(mb + row) * 64 + cc] = o4;
            }
        }
    } else {
        // ---- type K: dual 32x64 GEMM (Km, Kv) single pipeline + feat ----
        const int op = o - 32;                  // 0..15
        const int h  = (op >> 3) * 8 + x;       // head 0..15
        const int m  = op & 7;                  // m-eighth 0..7
        const int mb = m * 32;
        const int nb = h * 64;
        f32x4 okm[2], okv[2];
        gemmK_dual(a.mu, a.var, a.W[2], a.W[3], mb, nb, smem, t, okm, okv);
        const f32x4 bkm = *(const f32x4*)&a.bias[2][nb + cc];
        const f32x4 bkv = *(const f32x4*)&a.bias[3][nb + cc];
#pragma unroll
        for (int i = 0; i < 2; ++i) {
            const int row = (t >> 4) + i * 16;
            const int katt = mb + row;
            const f32x4 km  = okm[i] + bkm;
            const f32x4 kvr = okv[i] + bkv;
            bf16x4 o1, o2;
            float c = 0.f;
#pragma unroll
            for (int e = 0; e < 4; ++e) {
                const float kv = softplus_f(kvr[e]);
                const float r  = 0.5f * fast_rcp(kv);
                o1[e] = (bf16_t)r;
                o2[e] = (bf16_t)(-2.f * km[e] * r);
                c += km[e] * km[e] * r + 0.5f * __logf(kv);
            }
            bf16_t* grow = a.Gbf + ((size_t)(h * 256 + katt)) * 128;
            *(bf16x4*)&grow[cc]      = o1;
            *(bf16x4*)&grow[64 + cc] = o2;
#pragma unroll
            for (int off = 8; off > 0; off >>= 1)
                c += __shfl_xor(c, off, 16);
            if ((t & 15) == 0)
                a.cvec[h * 256 + katt] = c;
        }
    }
}

// ============================================================================
// attention (verified attn_v7 body); V inputs now bf16 [head][katt][64]
// ============================================================================
#define OFF_VM   0
#define OFF_VV   36864
#define OFF_FS   73728
#define OFF_SC   82176
#define OFF_PHI  98816
#define OFF_PLO  107264
#define OFF_P2H  115712
#define OFF_P2L  124160
#define ATTN_SMEM 132608

__global__ __launch_bounds__(512) void attn_v7(const float* __restrict__ Qm,
                                               const float* __restrict__ Qv,
                                               const bf16_t* __restrict__ Gbf,
                                               const float* __restrict__ cvec,
                                               const bf16_t* __restrict__ Vbm,
                                               const bf16_t* __restrict__ Vbv,
                                               bf16_t* __restrict__ Omu,
                                               bf16_t* __restrict__ Ovar) {
    __shared__ __align__(16) unsigned char smem[ATTN_SMEM];
    bf16_t* Vsm = (bf16_t*)(smem + OFF_VM);   // [256][72] bf16
    bf16_t* Vsv = (bf16_t*)(smem + OFF_VV);
    float*  Fs  = (float*)(smem + OFF_FS);    // [16][132] f32
    float*  Sc  = (float*)(smem + OFF_SC);    // [16][260] f32
    bf16_t* Phi = (bf16_t*)(smem + OFF_PHI);  // [16][264] bf16
    bf16_t* Plo = (bf16_t*)(smem + OFF_PLO);
    bf16_t* P2h = (bf16_t*)(smem + OFF_P2H);
    bf16_t* P2l = (bf16_t*)(smem + OFF_P2L);

    const int L = blockIdx.x;
    const int h  = ((L >> 7) << 3) + (L & 7);
    const int qt = (L >> 3) & 15;

    const int t = threadIdx.x, w = t >> 6, lane = t & 63;
    const int fr = lane & 15, fq = lane >> 4;
    const int n0 = w * 32;

    const bf16_t* gB = Gbf + ((size_t)(h * 256 + n0 + fr)) * 128 + fq * 8;

    bf16x8 bcur[4];
#pragma unroll
    for (int ks = 0; ks < 4; ++ks) bcur[ks] = *(const bf16x8*)(gB + ks * 32);

    if (t < 256) {
        const int r = t >> 4, c = t & 15;
        f32x4 qm = *(const f32x4*)(Qm + (size_t)(qt * 16 + r) * 1024 + h * 64 + c * 4);
        f32x4 qv = *(const f32x4*)(Qv + (size_t)(qt * 16 + r) * 1024 + h * 64 + c * 4);
        *(f32x4*)&Fs[r * 132 + c * 4]      = qm * qm + qv;
        *(f32x4*)&Fs[r * 132 + 64 + c * 4] = qm;
    }
    __syncthreads();

    bf16x8 ahi[4], alo[4];
#pragma unroll
    for (int ks = 0; ks < 4; ++ks) {
        f32x4 f0 = *(const f32x4*)&Fs[fr * 132 + ks * 32 + fq * 8];
        f32x4 f1 = *(const f32x4*)&Fs[fr * 132 + ks * 32 + fq * 8 + 4];
#pragma unroll
        for (int e = 0; e < 4; ++e) {
            bf16_t hb = (bf16_t)f0[e];
            ahi[ks][e] = hb; alo[ks][e] = (bf16_t)(f0[e] - (float)hb);
            bf16_t hb2 = (bf16_t)f1[e];
            ahi[ks][e + 4] = hb2; alo[ks][e + 4] = (bf16_t)(f1[e] - (float)hb2);
        }
    }

    const int tm = t & 255;
    const int vk = tm >> 2, vpart = tm & 3;
    const bf16_t* Vsrc = ((t >= 256) ? Vbv : Vbm) + (size_t)h * 16384;
    bf16_t*      Vdst = (t >= 256) ? Vsv : Vsm;

#pragma unroll
    for (int nt = 0; nt < 2; ++nt) {
        const int ra = vk + (2 * nt) * 64;
        const int rb = vk + (2 * nt + 1) * 64;
        // V already bf16: straight 16B copies, no conversion
        bf16x8 pa0 = *(const bf16x8*)(Vsrc + (size_t)ra * 64 + vpart * 16);
        bf16x8 pa1 = *(const bf16x8*)(Vsrc + (size_t)ra * 64 + vpart * 16 + 8);
        bf16x8 pb0 = *(const bf16x8*)(Vsrc + (size_t)rb * 64 + vpart * 16);
        bf16x8 pb1 = *(const bf16x8*)(Vsrc + (size_t)rb * 64 + vpart * 16 + 8);

        bf16x8 bnxt[4];
        if (nt < 1) {
#pragma unroll
            for (int ks = 0; ks < 4; ++ks)
                bnxt[ks] = *(const bf16x8*)(gB + 2048 + ks * 32);
        }

        f32x4 acc = {0.f, 0.f, 0.f, 0.f};
#pragma unroll
        for (int ks = 0; ks < 4; ++ks) {
            acc = __builtin_amdgcn_mfma_f32_16x16x32_bf16(ahi[ks], bcur[ks], acc, 0, 0, 0);
            acc = __builtin_amdgcn_mfma_f32_16x16x32_bf16(alo[ks], bcur[ks], acc, 0, 0, 0);
        }

        {
            bf16_t* da = Vdst + ra * 72 + vpart * 16;
            bf16_t* db = Vdst + rb * 72 + vpart * 16;
            *(bf16x8*)(da)     = pa0;
            *(bf16x8*)(da + 8) = pa1;
            *(bf16x8*)(db)     = pb0;
            *(bf16x8*)(db + 8) = pb1;
        }

        const float cv = cvec[h * 256 + n0 + nt * 16 + fr];
        f32x4 lg = (acc + cv) * (-0.125f);
#pragma unroll
        for (int reg = 0; reg < 4; ++reg)
            Sc[(fq * 4 + reg) * 260 + n0 + nt * 16 + fr] = lg[reg];

#pragma unroll
        for (int ks = 0; ks < 4; ++ks) bcur[ks] = bnxt[ks];
    }
    __syncthreads();

    const int fw = w * 2;
    f32x4 sr[2];
#pragma unroll
    for (int r = 0; r < 2; ++r)
        sr[r] = *(const f32x4*)&Sc[(fw + r) * 260 + lane * 4];
#pragma unroll
    for (int r = 0; r < 2; ++r) {
        f32x4 s = sr[r];
        float mloc = fmaxf(fmaxf(s[0], s[1]), fmaxf(s[2], s[3]));
#pragma unroll
        for (int off = 32; off > 0; off >>= 1)
            mloc = fmaxf(mloc, __shfl_xor(mloc, off, 64));
        s[0] = __expf(s[0] - mloc); s[1] = __expf(s[1] - mloc);
        s[2] = __expf(s[2] - mloc); s[3] = __expf(s[3] - mloc);
        float sl = (s[0] + s[1]) + (s[2] + s[3]);
#pragma unroll
        for (int off = 32; off > 0; off >>= 1)
            sl += __shfl_xor(sl, off, 64);
        sr[r] = s * fast_rcp(sl);
    }

#pragma unroll
    for (int r = 0; r < 2; ++r) {
        bf16x4 phi, plo, p2hi, p2lo;
#pragma unroll
        for (int e = 0; e < 4; ++e) {
            const float p = sr[r][e];
            const bf16_t hb = (bf16_t)p;
            phi[e] = hb; plo[e] = (bf16_t)(p - (float)hb);
            const float p2 = p * p;
            const bf16_t h2 = (bf16_t)p2;
            p2hi[e] = h2; p2lo[e] = (bf16_t)(p2 - (float)h2);
        }
        const int row = fw + r;
        *(bf16x4*)&Phi[row * 264 + lane * 4] = phi;
        *(bf16x4*)&Plo[row * 264 + lane * 4] = plo;
        *(bf16x4*)&P2h[row * 264 + lane * 4] = p2hi;
        *(bf16x4*)&P2l[row * 264 + lane * 4] = p2lo;
    }
    __syncthreads();

    const int tile = w & 3;
    const int isvar = w >> 2;
    const bf16_t* Pa = isvar ? P2h : Phi;
    const bf16_t* Pb = isvar ? P2l : Plo;
    const bf16_t* Vs = isvar ? Vsv : Vsm;
    f32x4 accp = {0.f, 0.f, 0.f, 0.f};
#pragma unroll
    for (int k0 = 0; k0 < 256; k0 += 32) {
        const int ka = k0 + fq * 8;
        bf16x8 a1 = *(const bf16x8*)&Pa[fr * 264 + ka];
        bf16x8 a2 = *(const bf16x8*)&Pb[fr * 264 + ka];
        bf16x8 bfr;
#pragma unroll
        for (int j = 0; j < 8; ++j)
            bfr[j] = Vs[(ka + j) * 72 + tile * 16 + fr];
        accp = __builtin_amdgcn_mfma_f32_16x16x32_bf16(a1, bfr, accp, 0, 0, 0);
        accp = __builtin_amdgcn_mfma_f32_16x16x32_bf16(a2, bfr, accp, 0, 0, 0);
    }

    bf16_t* Out = isvar ? Ovar : Omu;
#pragma unroll
    for (int reg = 0; reg < 4; ++reg) {
        const int qg = qt * 16 + fq * 4 + reg;
        const size_t ob = (size_t)qg * 1024 + h * 64 + tile * 16 + fr;
        Out[ob] = (bf16_t)accp[reg];
    }
}

// ============================================================================
// output projection: 1D grid, 128 blocks, XCD co-scheduling on (z,nb)
// ============================================================================
struct OutArgs {
    const bf16_t* A[2];
    const float*  W[2];
    const float*  bias[2];
    float*        dst[2];
    int           splus[2];
};

__global__ __launch_bounds__(256, 2) void out_gemm(OutArgs args) {
    __shared__ __align__(16) unsigned char smem[73728];
    const int t = threadIdx.x;
    const int L = blockIdx.x;
    const int x = L & 7, o = L >> 3;
    const int g = (o >> 2) * 8 + x;
    const int m = o & 3;
    const int z = g >> 4;
    const int n_base = (g & 15) * 64;
    const int m_base = m * 64;

    const bf16_t* __restrict__ A    = args.A[z];
    const float*  __restrict__ W    = args.W[z];
    const float*  __restrict__ bias = args.bias[z];
    float*        __restrict__ dst  = args.dst[z];
    const int sp = args.splus[z];

    f32x4 ov[4];
    gemmT_core<false, 4>(A, W, m_base, n_base, smem, t, ov);

    const int cc = (t & 15) * 4;
    const f32x4 bv = *(const f32x4*)&bias[n_base + cc];
#pragma unroll
    for (int i = 0; i < 4; ++i) {
        const int row = (t >> 4) + i * 16;
        f32x4 v = ov[i] + bv;
        if (sp) {
            v[0] = softplus_f(v[0]); v[1] = softplus_f(v[1]);
            v[2] = softplus_f(v[2]); v[3] = softplus_f(v[3]);
        }
        *(f32x4*)&dst[(size_t)(m_base + row) * 1024 + n_base + cc] = v;
    }
}

// ---------------- launch ----------------
extern "C" void kernel_launch(void* const* d_in, const int* in_sizes, int n_in,
                              void* d_out, int out_size, void* d_ws, size_t ws_size,
                              hipStream_t stream) {
    const float* mu  = (const float*)d_in[0];
    const float* var = (const float*)d_in[1];
    uint8_t* ws = (uint8_t*)d_ws;

    float*  Proj = (float*)(ws);                               // 2 x 1 MB: Qm, Qv (f32)
    bf16_t* Vbm  = (bf16_t*)(ws + (2u << 20));                 // 512 KB [16][256][64]
    bf16_t* Vbv  = (bf16_t*)(ws + (2u << 20) + (512u << 10));  // 512 KB
    bf16_t* Obm  = (bf16_t*)(ws + (3u << 20));                 // 512 KB
    bf16_t* Obv  = (bf16_t*)(ws + (3u << 20) + (512u << 10));  // 512 KB
    bf16_t* Gbf  = (bf16_t*)(ws + (4u << 20));                 // 1 MB
    float*  cvec = (float*)(ws + (5u << 20));                  // 16 KB

    // 1) projections; K fused with feat (single dual pipeline); V stored bf16
    ProjArgs pr;
    pr.mu = mu; pr.var = var;
    for (int i = 0; i < 6; ++i) {
        pr.W[i]    = (const float*)d_in[2 + 2 * i];
        pr.bias[i] = (const float*)d_in[3 + 2 * i];
    }
    pr.Proj = Proj; pr.Vbm = Vbm; pr.Vbv = Vbv; pr.Gbf = Gbf; pr.cvec = cvec;
    proj_kernel<<<dim3(384), 256, 0, stream>>>(pr);

    // 2) attention
    attn_v7<<<dim3(256), 512, 0, stream>>>(Proj, Proj + 262144, Gbf, cvec,
                                           Vbm, Vbv, Obm, Obv);

    // 3) output projections
    OutArgs g3;
    g3.A[0] = Obm;  g3.W[0] = (const float*)d_in[14];
    g3.bias[0] = (const float*)d_in[15];
    g3.dst[0] = (float*)d_out;             g3.splus[0] = 0;
    g3.A[1] = Obv;  g3.W[1] = (const float*)d_in[16];
    g3.bias[1] = (const float*)d_in[17];
    g3.dst[1] = (float*)d_out + 262144;    g3.splus[1] = 1;
    out_gemm<<<dim3(128), 256, 0, stream>>>(g3);
}

// Round 6
// 137.110 us; speedup vs baseline: 2.8888x; 1.0408x over previous
//
#include <hip/hip_runtime.h>
#include <math.h>

typedef __bf16 bf16_t;
typedef bf16_t bf16x4 __attribute__((ext_vector_type(4)));
typedef bf16_t bf16x8 __attribute__((ext_vector_type(8)));
typedef float  f32x4  __attribute__((ext_vector_type(4)));

__device__ __forceinline__ float softplus_f(float x) {
    return (x > 20.f) ? x : log1pf(expf(x));
}

__device__ __forceinline__ float fast_rcp(float x) {
#if __has_builtin(__builtin_amdgcn_rcpf)
    return __builtin_amdgcn_rcpf(x);
#else
    return 1.0f / x;
#endif
}

// ============================================================================
// 4-wave GEMM core, on-the-fly B transpose (verified R3-R5 structure).
// MT = 16-row output groups. Compact LDS: per-wave stage = MT*1152 + 4608
// bf16 elements (As MT*16 rows x 72, Bs 64 x 72); Cr wave stride MT*1088 f32.
// Split-K 256/wave, 4 slices, register prefetch. out[i] raw sums, order
// (s0+s1)+(s2+s3) — bit-identical to prior rounds.
// ============================================================================
template<bool AF32, int MT>
__device__ __forceinline__ void gemmT_core(const void* Aptr, const float* __restrict__ Wf,
                                           const int m_base, const int n_base,
                                           unsigned char* smem, const int t, f32x4* out) {
    constexpr int NA  = 2 * MT;
    constexpr int SWS = MT * 1152 + 4608;   // stage wave stride (bf16 elements)
    constexpr int CRS = MT * 1088;          // Cr wave stride (f32)
    __syncthreads();
    bf16_t* stage = (bf16_t*)smem;
    float*  Cr    = (float*)smem;
    const int lane = t & 63, w = t >> 6;
    bf16_t* As = stage + w * SWS;
    bf16_t* Bs = As + MT * 1152;
    const int r8 = lane >> 3, kb = lane & 7;
    const int fr = lane & 15, fq = lane >> 4, fk = fq * 8;
    const int bc = fr;
    const int br16 = fq * 16;

    const float*  Af = (const float*)Aptr  + (size_t)m_base * 1024 + w * 256 + kb * 8;
    const bf16_t* Ab = (const bf16_t*)Aptr + (size_t)m_base * 1024 + w * 256 + kb * 8;
    const float*  Bf = Wf + (size_t)(w * 256 + br16) * 1024 + n_base + bc * 4;

    f32x4 acc[MT][4] = {};
    bf16x8 pa[NA];
    f32x4 paf0[NA], paf1[NA];
    f32x4 pbf[16];

#pragma unroll
    for (int i = 0; i < NA; ++i) {
        if constexpr (AF32) {
            paf0[i] = *(const f32x4*)(Af + (size_t)(i * 8 + r8) * 1024);
            paf1[i] = *(const f32x4*)(Af + (size_t)(i * 8 + r8) * 1024 + 4);
        } else {
            pa[i] = *(const bf16x8*)(Ab + (size_t)(i * 8 + r8) * 1024);
        }
    }
#pragma unroll
    for (int i = 0; i < 16; ++i)
        pbf[i] = *(const f32x4*)(Bf + (size_t)i * 1024);

#pragma unroll
    for (int s = 0; s < 4; ++s) {
#pragma unroll
        for (int i = 0; i < NA; ++i) {
            bf16x8 av;
            if constexpr (AF32) {
#pragma unroll
                for (int e = 0; e < 4; ++e) {
                    av[e]     = (bf16_t)paf0[i][e];
                    av[e + 4] = (bf16_t)paf1[i][e];
                }
            } else {
                av = pa[i];
            }
            *(bf16x8*)&As[(i * 8 + r8) * 72 + kb * 8] = av;
        }
#pragma unroll
        for (int e = 0; e < 4; ++e) {
            bf16x8 lo, hi;
#pragma unroll
            for (int q = 0; q < 8; ++q) {
                lo[q] = (bf16_t)pbf[q][e];
                hi[q] = (bf16_t)pbf[q + 8][e];
            }
            *(bf16x8*)&Bs[(bc * 4 + e) * 72 + br16]     = lo;
            *(bf16x8*)&Bs[(bc * 4 + e) * 72 + br16 + 8] = hi;
        }
        if (s < 3) {
            const int off = (s + 1) * 64;
#pragma unroll
            for (int i = 0; i < NA; ++i) {
                if constexpr (AF32) {
                    paf0[i] = *(const f32x4*)(Af + (size_t)(i * 8 + r8) * 1024 + off);
                    paf1[i] = *(const f32x4*)(Af + (size_t)(i * 8 + r8) * 1024 + off + 4);
                } else {
                    pa[i] = *(const bf16x8*)(Ab + (size_t)(i * 8 + r8) * 1024 + off);
                }
            }
#pragma unroll
            for (int i = 0; i < 16; ++i)
                pbf[i] = *(const f32x4*)(Bf + (size_t)i * 1024 + (size_t)off * 1024);
        }
#pragma unroll
        for (int kh = 0; kh < 2; ++kh) {
            bf16x8 aF[MT], bF[4];
#pragma unroll
            for (int i = 0; i < MT; ++i)
                aF[i] = *(const bf16x8*)&As[(i * 16 + fr) * 72 + kh * 32 + fk];
#pragma unroll
            for (int j = 0; j < 4; ++j)
                bF[j] = *(const bf16x8*)&Bs[(j * 16 + fr) * 72 + kh * 32 + fk];
#pragma unroll
            for (int i = 0; i < MT; ++i)
#pragma unroll
                for (int j = 0; j < 4; ++j)
                    acc[i][j] = __builtin_amdgcn_mfma_f32_16x16x32_bf16(aF[i], bF[j], acc[i][j], 0, 0, 0);
        }
    }

    __syncthreads();
    {
        float* Crw = Cr + w * CRS;
        const int orow = fq * 4;
#pragma unroll
        for (int i = 0; i < MT; ++i)
#pragma unroll
            for (int j = 0; j < 4; ++j)
#pragma unroll
                for (int rr = 0; rr < 4; ++rr)
                    Crw[(i * 16 + orow + rr) * 68 + j * 16 + fr] = acc[i][j][rr];
    }
    __syncthreads();

    const int cc = (t & 15) * 4;
#pragma unroll
    for (int i = 0; i < MT; ++i) {
        const int row = (t >> 4) + i * 16;
        f32x4 s0 = *(const f32x4*)&Cr[0 * CRS + row * 68 + cc];
        f32x4 s1 = *(const f32x4*)&Cr[1 * CRS + row * 68 + cc];
        f32x4 s2 = *(const f32x4*)&Cr[2 * CRS + row * 68 + cc];
        f32x4 s3 = *(const f32x4*)&Cr[3 * CRS + row * 68 + cc];
        out[i] = (s0 + s1) + (s2 + s3);
    }
}

// ============================================================================
// Dual-GEMM K core (verified R5): ONE 8-slice pipeline, waves 0-1 Km / 2-3 Kv,
// split-K 512 each. 32-row tile. Compact LDS (same strides as MT=2 core).
// ============================================================================
__device__ __forceinline__ void gemmK_dual(const float* __restrict__ mu,
                                           const float* __restrict__ var,
                                           const float* __restrict__ Wkm,
                                           const float* __restrict__ Wkv,
                                           const int m_base, const int n_base,
                                           unsigned char* smem, const int t,
                                           f32x4 okm[2], f32x4 okv[2]) {
    constexpr int SWS = 2 * 1152 + 4608;
    constexpr int CRS = 2 * 1088;
    __syncthreads();
    bf16_t* stage = (bf16_t*)smem;
    float*  Cr    = (float*)smem;
    const int lane = t & 63, w = t >> 6;
    bf16_t* As = stage + w * SWS;
    bf16_t* Bs = As + 2 * 1152;
    const int r8 = lane >> 3, kb = lane & 7;
    const int fr = lane & 15, fq = lane >> 4, fk = fq * 8;
    const int bc = fr;
    const int br16 = fq * 16;

    const float* Asrc = (w < 2) ? mu : var;
    const float* Wsrc = (w < 2) ? Wkm : Wkv;
    const int kbase = (w & 1) * 512;

    const float* Af = Asrc + (size_t)m_base * 1024 + kbase + kb * 8;
    const float* Bf = Wsrc + (size_t)(kbase + br16) * 1024 + n_base + bc * 4;

    f32x4 acc[2][4] = {};
    f32x4 paf0[4], paf1[4];
    f32x4 pbf[16];

#pragma unroll
    for (int i = 0; i < 4; ++i) {
        paf0[i] = *(const f32x4*)(Af + (size_t)(i * 8 + r8) * 1024);
        paf1[i] = *(const f32x4*)(Af + (size_t)(i * 8 + r8) * 1024 + 4);
    }
#pragma unroll
    for (int i = 0; i < 16; ++i)
        pbf[i] = *(const f32x4*)(Bf + (size_t)i * 1024);

#pragma unroll
    for (int s = 0; s < 8; ++s) {
#pragma unroll
        for (int i = 0; i < 4; ++i) {
            bf16x8 av;
#pragma unroll
            for (int e = 0; e < 4; ++e) {
                av[e]     = (bf16_t)paf0[i][e];
                av[e + 4] = (bf16_t)paf1[i][e];
            }
            *(bf16x8*)&As[(i * 8 + r8) * 72 + kb * 8] = av;
        }
#pragma unroll
        for (int e = 0; e < 4; ++e) {
            bf16x8 lo, hi;
#pragma unroll
            for (int q = 0; q < 8; ++q) {
                lo[q] = (bf16_t)pbf[q][e];
                hi[q] = (bf16_t)pbf[q + 8][e];
            }
            *(bf16x8*)&Bs[(bc * 4 + e) * 72 + br16]     = lo;
            *(bf16x8*)&Bs[(bc * 4 + e) * 72 + br16 + 8] = hi;
        }
        if (s < 7) {
            const int off = (s + 1) * 64;
#pragma unroll
            for (int i = 0; i < 4; ++i) {
                paf0[i] = *(const f32x4*)(Af + (size_t)(i * 8 + r8) * 1024 + off);
                paf1[i] = *(const f32x4*)(Af + (size_t)(i * 8 + r8) * 1024 + off + 4);
            }
#pragma unroll
            for (int i = 0; i < 16; ++i)
                pbf[i] = *(const f32x4*)(Bf + (size_t)i * 1024 + (size_t)off * 1024);
        }
#pragma unroll
        for (int kh = 0; kh < 2; ++kh) {
            bf16x8 aF[2], bF[4];
#pragma unroll
            for (int i = 0; i < 2; ++i)
                aF[i] = *(const bf16x8*)&As[(i * 16 + fr) * 72 + kh * 32 + fk];
#pragma unroll
            for (int j = 0; j < 4; ++j)
                bF[j] = *(const bf16x8*)&Bs[(j * 16 + fr) * 72 + kh * 32 + fk];
#pragma unroll
            for (int i = 0; i < 2; ++i)
#pragma unroll
                for (int j = 0; j < 4; ++j)
                    acc[i][j] = __builtin_amdgcn_mfma_f32_16x16x32_bf16(aF[i], bF[j], acc[i][j], 0, 0, 0);
        }
    }

    __syncthreads();
    {
        float* Crw = Cr + w * CRS;
        const int orow = fq * 4;
#pragma unroll
        for (int i = 0; i < 2; ++i)
#pragma unroll
            for (int j = 0; j < 4; ++j)
#pragma unroll
                for (int rr = 0; rr < 4; ++rr)
                    Crw[(i * 16 + orow + rr) * 68 + j * 16 + fr] = acc[i][j][rr];
    }
    __syncthreads();

    const int cc = (t & 15) * 4;
#pragma unroll
    for (int i = 0; i < 2; ++i) {
        const int row = (t >> 4) + i * 16;
        okm[i] = *(const f32x4*)&Cr[0 * CRS + row * 68 + cc]
               + *(const f32x4*)&Cr[1 * CRS + row * 68 + cc];
        okv[i] = *(const f32x4*)&Cr[2 * CRS + row * 68 + cc]
               + *(const f32x4*)&Cr[3 * CRS + row * 68 + cc];
    }
}

// ============================================================================
// proj: 1D grid, 640 blocks, all 32-row tiles, K blocks FIRST (long poles).
//  L 0..127   type-K: dual 32x64 (Km+Kv) + feat. x=L&7, o=L>>3:
//             h = (o>>3)*8 + x (heads co-scheduled per XCD), m = o&7.
//  L 128..639 type-A: 32x64 GEMM (zp 0:Qm 1:Qv 2:Vm 3:Vv). L'=L-128:
//             panel = (o>>3)*8 + x  (zp = panel>>4, nb = (panel&15)*64), m = o&7.
// ============================================================================
#define PROJ_SMEM 55296   // 4 waves * (2304 As + 4608 Bs) * 2B; Cr 34816 fits under

struct ProjArgs {
    const float* mu; const float* var;
    const float* W[6];
    const float* bias[6];
    float* Proj;                // slots: 0 Qm, 1 Qv (f32)
    bf16_t* Vbm; bf16_t* Vbv;   // [16 head][256 katt][64 d] bf16
    bf16_t* Gbf; float* cvec;
};

__global__ __launch_bounds__(256, 2) void proj_kernel(ProjArgs a) {
    __shared__ __align__(16) unsigned char smem[PROJ_SMEM];
    const int t = threadIdx.x;
    const int cc = (t & 15) * 4;
    const int L = blockIdx.x;

    if (L < 128) {
        // ---- type K ----
        const int x = L & 7, o = L >> 3;
        const int h  = (o >> 3) * 8 + x;
        const int mb = (o & 7) * 32;
        const int nb = h * 64;
        f32x4 okm[2], okv[2];
        gemmK_dual(a.mu, a.var, a.W[2], a.W[3], mb, nb, smem, t, okm, okv);
        const f32x4 bkm = *(const f32x4*)&a.bias[2][nb + cc];
        const f32x4 bkv = *(const f32x4*)&a.bias[3][nb + cc];
#pragma unroll
        for (int i = 0; i < 2; ++i) {
            const int row = (t >> 4) + i * 16;
            const int katt = mb + row;
            const f32x4 km  = okm[i] + bkm;
            const f32x4 kvr = okv[i] + bkv;
            bf16x4 o1, o2;
            float c = 0.f;
#pragma unroll
            for (int e = 0; e < 4; ++e) {
                const float kv = softplus_f(kvr[e]);
                const float r  = 0.5f * fast_rcp(kv);
                o1[e] = (bf16_t)r;
                o2[e] = (bf16_t)(-2.f * km[e] * r);
                c += km[e] * km[e] * r + 0.5f * __logf(kv);
            }
            bf16_t* grow = a.Gbf + ((size_t)(h * 256 + katt)) * 128;
            *(bf16x4*)&grow[cc]      = o1;
            *(bf16x4*)&grow[64 + cc] = o2;
#pragma unroll
            for (int off = 8; off > 0; off >>= 1)
                c += __shfl_xor(c, off, 16);
            if ((t & 15) == 0)
                a.cvec[h * 256 + katt] = c;
        }
    } else {
        // ---- type A (32-row tile) ----
        const int Lp = L - 128;
        const int x = Lp & 7, o = Lp >> 3;
        const int panel = (o >> 3) * 8 + x;     // 0..63
        const int mb = (o & 7) * 32;
        const int zp = panel >> 4;              // 0:Qm 1:Qv 2:Vm 3:Vv
        const int nb = (panel & 15) * 64;
        const int wi = (zp < 2) ? zp : (zp + 2);
        const int sp = (zp == 1) || (zp == 3);
        const void* A = sp ? (const void*)a.var : (const void*)a.mu;
        f32x4 ov[2];
        gemmT_core<true, 2>(A, a.W[wi], mb, nb, smem, t, ov);
        const f32x4 bv = *(const f32x4*)&a.bias[wi][nb + cc];
        if (zp < 2) {
            float* dst = a.Proj + (size_t)zp * 262144;
#pragma unroll
            for (int i = 0; i < 2; ++i) {
                const int row = (t >> 4) + i * 16;
                f32x4 v = ov[i] + bv;
                if (sp) {
                    v[0] = softplus_f(v[0]); v[1] = softplus_f(v[1]);
                    v[2] = softplus_f(v[2]); v[3] = softplus_f(v[3]);
                }
                *(f32x4*)&dst[(size_t)(mb + row) * 1024 + nb + cc] = v;
            }
        } else {
            bf16_t* dst = ((zp == 2) ? a.Vbm : a.Vbv) + (size_t)(nb >> 6) * 16384;
#pragma unroll
            for (int i = 0; i < 2; ++i) {
                const int row = (t >> 4) + i * 16;
                f32x4 v = ov[i] + bv;
                if (sp) {
                    v[0] = softplus_f(v[0]); v[1] = softplus_f(v[1]);
                    v[2] = softplus_f(v[2]); v[3] = softplus_f(v[3]);
                }
                bf16x4 o4;
                o4[0] = (bf16_t)v[0]; o4[1] = (bf16_t)v[1];
                o4[2] = (bf16_t)v[2]; o4[3] = (bf16_t)v[3];
                *(bf16x4*)&dst[(size_t)(mb + row) * 64 + cc] = o4;
            }
        }
    }
}

// ============================================================================
// attention (verified attn_v7 body, unchanged from R5)
// ============================================================================
#define OFF_VM   0
#define OFF_VV   36864
#define OFF_FS   73728
#define OFF_SC   82176
#define OFF_PHI  98816
#define OFF_PLO  107264
#define OFF_P2H  115712
#define OFF_P2L  124160
#define ATTN_SMEM 132608

__global__ __launch_bounds__(512) void attn_v7(const float* __restrict__ Qm,
                                               const float* __restrict__ Qv,
                                               const bf16_t* __restrict__ Gbf,
                                               const float* __restrict__ cvec,
                                               const bf16_t* __restrict__ Vbm,
                                               const bf16_t* __restrict__ Vbv,
                                               bf16_t* __restrict__ Omu,
                                               bf16_t* __restrict__ Ovar) {
    __shared__ __align__(16) unsigned char smem[ATTN_SMEM];
    bf16_t* Vsm = (bf16_t*)(smem + OFF_VM);   // [256][72] bf16
    bf16_t* Vsv = (bf16_t*)(smem + OFF_VV);
    float*  Fs  = (float*)(smem + OFF_FS);    // [16][132] f32
    float*  Sc  = (float*)(smem + OFF_SC);    // [16][260] f32
    bf16_t* Phi = (bf16_t*)(smem + OFF_PHI);  // [16][264] bf16
    bf16_t* Plo = (bf16_t*)(smem + OFF_PLO);
    bf16_t* P2h = (bf16_t*)(smem + OFF_P2H);
    bf16_t* P2l = (bf16_t*)(smem + OFF_P2L);

    const int L = blockIdx.x;
    const int h  = ((L >> 7) << 3) + (L & 7);
    const int qt = (L >> 3) & 15;

    const int t = threadIdx.x, w = t >> 6, lane = t & 63;
    const int fr = lane & 15, fq = lane >> 4;
    const int n0 = w * 32;

    const bf16_t* gB = Gbf + ((size_t)(h * 256 + n0 + fr)) * 128 + fq * 8;

    bf16x8 bcur[4];
#pragma unroll
    for (int ks = 0; ks < 4; ++ks) bcur[ks] = *(const bf16x8*)(gB + ks * 32);

    if (t < 256) {
        const int r = t >> 4, c = t & 15;
        f32x4 qm = *(const f32x4*)(Qm + (size_t)(qt * 16 + r) * 1024 + h * 64 + c * 4);
        f32x4 qv = *(const f32x4*)(Qv + (size_t)(qt * 16 + r) * 1024 + h * 64 + c * 4);
        *(f32x4*)&Fs[r * 132 + c * 4]      = qm * qm + qv;
        *(f32x4*)&Fs[r * 132 + 64 + c * 4] = qm;
    }
    __syncthreads();

    bf16x8 ahi[4], alo[4];
#pragma unroll
    for (int ks = 0; ks < 4; ++ks) {
        f32x4 f0 = *(const f32x4*)&Fs[fr * 132 + ks * 32 + fq * 8];
        f32x4 f1 = *(const f32x4*)&Fs[fr * 132 + ks * 32 + fq * 8 + 4];
#pragma unroll
        for (int e = 0; e < 4; ++e) {
            bf16_t hb = (bf16_t)f0[e];
            ahi[ks][e] = hb; alo[ks][e] = (bf16_t)(f0[e] - (float)hb);
            bf16_t hb2 = (bf16_t)f1[e];
            ahi[ks][e + 4] = hb2; alo[ks][e + 4] = (bf16_t)(f1[e] - (float)hb2);
        }
    }

    const int tm = t & 255;
    const int vk = tm >> 2, vpart = tm & 3;
    const bf16_t* Vsrc = ((t >= 256) ? Vbv : Vbm) + (size_t)h * 16384;
    bf16_t*      Vdst = (t >= 256) ? Vsv : Vsm;

#pragma unroll
    for (int nt = 0; nt < 2; ++nt) {
        const int ra = vk + (2 * nt) * 64;
        const int rb = vk + (2 * nt + 1) * 64;
        bf16x8 pa0 = *(const bf16x8*)(Vsrc + (size_t)ra * 64 + vpart * 16);
        bf16x8 pa1 = *(const bf16x8*)(Vsrc + (size_t)ra * 64 + vpart * 16 + 8);
        bf16x8 pb0 = *(const bf16x8*)(Vsrc + (size_t)rb * 64 + vpart * 16);
        bf16x8 pb1 = *(const bf16x8*)(Vsrc + (size_t)rb * 64 + vpart * 16 + 8);

        bf16x8 bnxt[4];
        if (nt < 1) {
#pragma unroll
            for (int ks = 0; ks < 4; ++ks)
                bnxt[ks] = *(const bf16x8*)(gB + 2048 + ks * 32);
        }

        f32x4 acc = {0.f, 0.f, 0.f, 0.f};
#pragma unroll
        for (int ks = 0; ks < 4; ++ks) {
            acc = __builtin_amdgcn_mfma_f32_16x16x32_bf16(ahi[ks], bcur[ks], acc, 0, 0, 0);
            acc = __builtin_amdgcn_mfma_f32_16x16x32_bf16(alo[ks], bcur[ks], acc, 0, 0, 0);
        }

        {
            bf16_t* da = Vdst + ra * 72 + vpart * 16;
            bf16_t* db = Vdst + rb * 72 + vpart * 16;
            *(bf16x8*)(da)     = pa0;
            *(bf16x8*)(da + 8) = pa1;
            *(bf16x8*)(db)     = pb0;
            *(bf16x8*)(db + 8) = pb1;
        }

        const float cv = cvec[h * 256 + n0 + nt * 16 + fr];
        f32x4 lg = (acc + cv) * (-0.125f);
#pragma unroll
        for (int reg = 0; reg < 4; ++reg)
            Sc[(fq * 4 + reg) * 260 + n0 + nt * 16 + fr] = lg[reg];

#pragma unroll
        for (int ks = 0; ks < 4; ++ks) bcur[ks] = bnxt[ks];
    }
    __syncthreads();

    const int fw = w * 2;
    f32x4 sr[2];
#pragma unroll
    for (int r = 0; r < 2; ++r)
        sr[r] = *(const f32x4*)&Sc[(fw + r) * 260 + lane * 4];
#pragma unroll
    for (int r = 0; r < 2; ++r) {
        f32x4 s = sr[r];
        float mloc = fmaxf(fmaxf(s[0], s[1]), fmaxf(s[2], s[3]));
#pragma unroll
        for (int off = 32; off > 0; off >>= 1)
            mloc = fmaxf(mloc, __shfl_xor(mloc, off, 64));
        s[0] = __expf(s[0] - mloc); s[1] = __expf(s[1] - mloc);
        s[2] = __expf(s[2] - mloc); s[3] = __expf(s[3] - mloc);
        float sl = (s[0] + s[1]) + (s[2] + s[3]);
#pragma unroll
        for (int off = 32; off > 0; off >>= 1)
            sl += __shfl_xor(sl, off, 64);
        sr[r] = s * fast_rcp(sl);
    }

#pragma unroll
    for (int r = 0; r < 2; ++r) {
        bf16x4 phi, plo, p2hi, p2lo;
#pragma unroll
        for (int e = 0; e < 4; ++e) {
            const float p = sr[r][e];
            const bf16_t hb = (bf16_t)p;
            phi[e] = hb; plo[e] = (bf16_t)(p - (float)hb);
            const float p2 = p * p;
            const bf16_t h2 = (bf16_t)p2;
            p2hi[e] = h2; p2lo[e] = (bf16_t)(p2 - (float)h2);
        }
        const int row = fw + r;
        *(bf16x4*)&Phi[row * 264 + lane * 4] = phi;
        *(bf16x4*)&Plo[row * 264 + lane * 4] = plo;
        *(bf16x4*)&P2h[row * 264 + lane * 4] = p2hi;
        *(bf16x4*)&P2l[row * 264 + lane * 4] = p2lo;
    }
    __syncthreads();

    const int tile = w & 3;
    const int isvar = w >> 2;
    const bf16_t* Pa = isvar ? P2h : Phi;
    const bf16_t* Pb = isvar ? P2l : Plo;
    const bf16_t* Vs = isvar ? Vsv : Vsm;
    f32x4 accp = {0.f, 0.f, 0.f, 0.f};
#pragma unroll
    for (int k0 = 0; k0 < 256; k0 += 32) {
        const int ka = k0 + fq * 8;
        bf16x8 a1 = *(const bf16x8*)&Pa[fr * 264 + ka];
        bf16x8 a2 = *(const bf16x8*)&Pb[fr * 264 + ka];
        bf16x8 bfr;
#pragma unroll
        for (int j = 0; j < 8; ++j)
            bfr[j] = Vs[(ka + j) * 72 + tile * 16 + fr];
        accp = __builtin_amdgcn_mfma_f32_16x16x32_bf16(a1, bfr, accp, 0, 0, 0);
        accp = __builtin_amdgcn_mfma_f32_16x16x32_bf16(a2, bfr, accp, 0, 0, 0);
    }

    bf16_t* Out = isvar ? Ovar : Omu;
#pragma unroll
    for (int reg = 0; reg < 4; ++reg) {
        const int qg = qt * 16 + fq * 4 + reg;
        const size_t ob = (size_t)qg * 1024 + h * 64 + tile * 16 + fr;
        Out[ob] = (bf16_t)accp[reg];
    }
}

// ============================================================================
// output projection: 256 blocks (32-row tiles), exactly 1/CU, XCD co-sched
// ============================================================================
struct OutArgs {
    const bf16_t* A[2];
    const float*  W[2];
    const float*  bias[2];
    float*        dst[2];
    int           splus[2];
};

__global__ __launch_bounds__(256, 2) void out_gemm(OutArgs args) {
    __shared__ __align__(16) unsigned char smem[PROJ_SMEM];
    const int t = threadIdx.x;
    const int L = blockIdx.x;
    const int x = L & 7, o = L >> 3;            // o 0..31
    const int g = (o >> 3) * 8 + x;             // panel (z,nb) 0..31
    const int m = o & 7;
    const int z = g >> 4;
    const int n_base = (g & 15) * 64;
    const int m_base = m * 32;

    const bf16_t* __restrict__ A    = args.A[z];
    const float*  __restrict__ W    = args.W[z];
    const float*  __restrict__ bias = args.bias[z];
    float*        __restrict__ dst  = args.dst[z];
    const int sp = args.splus[z];

    f32x4 ov[2];
    gemmT_core<false, 2>(A, W, m_base, n_base, smem, t, ov);

    const int cc = (t & 15) * 4;
    const f32x4 bv = *(const f32x4*)&bias[n_base + cc];
#pragma unroll
    for (int i = 0; i < 2; ++i) {
        const int row = (t >> 4) + i * 16;
        f32x4 v = ov[i] + bv;
        if (sp) {
            v[0] = softplus_f(v[0]); v[1] = softplus_f(v[1]);
            v[2] = softplus_f(v[2]); v[3] = softplus_f(v[3]);
        }
        *(f32x4*)&dst[(size_t)(m_base + row) * 1024 + n_base + cc] = v;
    }
}

// ---------------- launch ----------------
extern "C" void kernel_launch(void* const* d_in, const int* in_sizes, int n_in,
                              void* d_out, int out_size, void* d_ws, size_t ws_size,
                              hipStream_t stream) {
    const float* mu  = (const float*)d_in[0];
    const float* var = (const float*)d_in[1];
    uint8_t* ws = (uint8_t*)d_ws;

    float*  Proj = (float*)(ws);                               // 2 x 1 MB: Qm, Qv (f32)
    bf16_t* Vbm  = (bf16_t*)(ws + (2u << 20));                 // 512 KB [16][256][64]
    bf16_t* Vbv  = (bf16_t*)(ws + (2u << 20) + (512u << 10));  // 512 KB
    bf16_t* Obm  = (bf16_t*)(ws + (3u << 20));                 // 512 KB
    bf16_t* Obv  = (bf16_t*)(ws + (3u << 20) + (512u << 10));  // 512 KB
    bf16_t* Gbf  = (bf16_t*)(ws + (4u << 20));                 // 1 MB
    float*  cvec = (float*)(ws + (5u << 20));                  // 16 KB

    // 1) projections; K blocks first (long poles), all 32-row tiles
    ProjArgs pr;
    pr.mu = mu; pr.var = var;
    for (int i = 0; i < 6; ++i) {
        pr.W[i]    = (const float*)d_in[2 + 2 * i];
        pr.bias[i] = (const float*)d_in[3 + 2 * i];
    }
    pr.Proj = Proj; pr.Vbm = Vbm; pr.Vbv = Vbv; pr.Gbf = Gbf; pr.cvec = cvec;
    proj_kernel<<<dim3(640), 256, 0, stream>>>(pr);

    // 2) attention
    attn_v7<<<dim3(256), 512, 0, stream>>>(Proj, Proj + 262144, Gbf, cvec,
                                           Vbm, Vbv, Obm, Obv);

    // 3) output projections
    OutArgs g3;
    g3.A[0] = Obm;  g3.W[0] = (const float*)d_in[14];
    g3.bias[0] = (const float*)d_in[15];
    g3.dst[0] = (float*)d_out;             g3.splus[0] = 0;
    g3.A[1] = Obv;  g3.W[1] = (const float*)d_in[16];
    g3.bias[1] = (const float*)d_in[17];
    g3.dst[1] = (float*)d_out + 262144;    g3.splus[1] = 1;
    out_gemm<<<dim3(256), 256, 0, stream>>>(g3);
}